// Round 6
// baseline (875.432 us; speedup 1.0000x reference)
//
#include <hip/hip_runtime.h>

// ChebNet K=3, W-first form: ChebConv(H) = H@(W0-W2) + S·(H@W1 + 2·S·(H@W2)).
// Round 18: (1) degree-balanced gathers -- nodes counting-sorted by degree
// (dhist in k_hist2, scan in k_scanB, scatter in k_perm); gathers process
// perm[vidx] so the 4 nodes of a wave have ~equal degree -> no wasted loop
// iterations. (2) launch fusion: wprep+drop+detect -> k_init; scanA folded
// into k_hist2 (blk_sum); scanC folded into k_place (local re-scan writes
// row_ptr). 14 -> 12 launches.

static constexpr int BLK = 256;
static constexpr int ROWB = 256;
static constexpr int RB_SHIFT = 8;
static constexpr int BCAP = 6144;
static constexpr int CHUNK = 8192;

typedef _Float16 f16x8 __attribute__((ext_vector_type(8)));
typedef _Float16 f16x2 __attribute__((ext_vector_type(2)));
typedef float f32x4 __attribute__((ext_vector_type(4)));

__device__ __forceinline__ unsigned rotl32(unsigned x, int r) {
    return (x << r) | (x >> (32 - r));
}

// JAX partitionable threefry word for element i:
// (b1,b2) = threefry2x32(key=(0,42), counter=(0,i)); word = b1 ^ b2.
__device__ __forceinline__ unsigned tf_word(unsigned i) {
    const unsigned ks0 = 0u;
    const unsigned ks1 = 42u;
    const unsigned ks2 = 0u ^ 42u ^ 0x1BD11BDAu;
    unsigned x0 = 0u + ks0;
    unsigned x1 = i + ks1;
#define TF_RND(r) { x0 += x1; x1 = rotl32(x1, (r)); x1 ^= x0; }
    TF_RND(13) TF_RND(15) TF_RND(26) TF_RND(6)
    x0 += ks1; x1 += ks2 + 1u;
    TF_RND(17) TF_RND(29) TF_RND(16) TF_RND(24)
    x0 += ks2; x1 += ks0 + 2u;
    TF_RND(13) TF_RND(15) TF_RND(26) TF_RND(6)
    x0 += ks0; x1 += ks1 + 3u;
    TF_RND(17) TF_RND(29) TF_RND(16) TF_RND(24)
    x0 += ks1; x1 += ks2 + 4u;
    TF_RND(13) TF_RND(15) TF_RND(26) TF_RND(6)
    x0 += ks2; x1 += ks0 + 5u;
#undef TF_RND
    return x0 ^ x1;
}

// f16 pack/unpack
__device__ __forceinline__ unsigned short f2h(float f) {
    union { _Float16 h; unsigned short u; } c; c.h = (_Float16)f; return c.u;
}
__device__ __forceinline__ unsigned pack2h(float a, float b) {
    union { f16x2 h; unsigned u; } c;
    c.h[0] = (_Float16)a; c.h[1] = (_Float16)b;
    return c.u;
}

// Fused init: blocks [0,gDrop) dropout mask; block gDrop int64-detect;
// blocks (gDrop, gDrop+72] weight prep (fp16, transposed, pre-XOR-swizzled).
__global__ void __launch_bounds__(256) k_init(int NW, const int* __restrict__ ei,
                                              const float* __restrict__ W1,
                                              const float* __restrict__ W2,
                                              int* __restrict__ flags,
                                              unsigned long long* __restrict__ dmask,
                                              unsigned short* __restrict__ wt1,
                                              unsigned short* __restrict__ wt2,
                                              int gDrop) {
    int b = blockIdx.x;
    int t = threadIdx.x;
    if (b < gDrop) {
        int idx = b * 256 + t;
        unsigned word = (idx < NW) ? tf_word((unsigned)idx) : 0u;
        unsigned long long bal = __ballot(word >> 31);
        if ((t & 63) == 0 && idx < NW) dmask[idx >> 6] = bal;
        return;
    }
    if (b == gDrop) {
        __shared__ int cnt_nz;
        if (t == 0) cnt_nz = 0;
        __syncthreads();
        if (ei[2 * t + 1] != 0) atomicAdd(&cnt_nz, 1);
        __syncthreads();
        if (t == 0) flags[0] = (cnt_nz == 0) ? 1 : 0;
        return;
    }
    int idx = (b - gDrop - 1) * 256 + t;
    if (idx < 12288) {
        int c = idx >> 6, r6 = idx & 63;
        int slot = (r6 >> 3) ^ (c & 7);
        int k = slot * 8 + (r6 & 7);
        float v;
        if (c < 64)       v = W1[k * 64 + c] - W1[8192 + k * 64 + c];
        else if (c < 128) v = W1[4096 + k * 64 + (c - 64)];
        else              v = W1[8192 + k * 64 + (c - 128)];
        wt1[idx] = f2h(v);
    } else {
        int j = idx - 12288;
        int c = j >> 6, r6 = j & 63;
        int slot = (r6 >> 3) ^ (c & 7);
        int k = slot * 8 + (r6 & 7);
        float v;
        if (c < 32)      v = W2[k * 32 + c] - W2[4096 + k * 32 + c];
        else if (c < 64) v = W2[2048 + k * 32 + (c - 32)];
        else             v = W2[4096 + k * 32 + (c - 64)];
        wt2[j] = f2h(v);
    }
}

// Pass 1: bin edges into row-buckets, LDS-staged for coalesced writes.
__global__ void __launch_bounds__(256) k_bin(const int* __restrict__ ei, int E,
                                             const int* __restrict__ flags,
                                             int* __restrict__ bcnt,
                                             unsigned* __restrict__ bdata, int NB) {
    __shared__ unsigned sval[CHUNK];
    __shared__ unsigned short sbkt[CHUNK];
    __shared__ int h[512], ex[512], cur[512], basep[512];
    int t = threadIdx.x;
    int start = blockIdx.x * CHUNK;
    int lim = min(CHUNK, E - start);
    bool i64 = flags[0] != 0;
    h[t] = 0; h[t + 256] = 0;
    __syncthreads();
    unsigned vv[32];
    unsigned short bb_[32];
#pragma unroll
    for (int k = 0; k < 32; ++k) {
        int idx = k * 256 + t;
        int e = start + idx;
        if (idx < lim) {
            int r, c;
            if (i64) { r = ei[2 * e]; c = ei[2 * (E + e)]; }
            else     { r = ei[e];     c = ei[E + e]; }
            int b = r >> RB_SHIFT;
            vv[k] = ((unsigned)(r & (ROWB - 1)) << 17) | (unsigned)c;
            bb_[k] = (unsigned short)b;
            atomicAdd(&h[b], 1);
        } else {
            bb_[k] = 0xFFFF;
        }
    }
    __syncthreads();
    int i0 = t, i1 = t + 256;
    ex[i0] = h[i0]; ex[i1] = h[i1];
    __syncthreads();
    for (int off = 1; off < 512; off <<= 1) {
        int v0 = (i0 >= off) ? ex[i0 - off] : 0;
        int v1 = (i1 >= off) ? ex[i1 - off] : 0;
        __syncthreads();
        ex[i0] += v0; ex[i1] += v1;
        __syncthreads();
    }
    int e0 = ex[i0] - h[i0], e1 = ex[i1] - h[i1];
    __syncthreads();
    ex[i0] = e0; cur[i0] = e0;
    ex[i1] = e1; cur[i1] = e1;
    if (i0 < NB && h[i0] > 0) basep[i0] = atomicAdd(&bcnt[i0], h[i0]);
    if (i1 < NB && h[i1] > 0) basep[i1] = atomicAdd(&bcnt[i1], h[i1]);
    __syncthreads();
#pragma unroll
    for (int k = 0; k < 32; ++k) {
        if (bb_[k] != 0xFFFF) {
            int p = atomicAdd(&cur[bb_[k]], 1);
            sval[p] = vv[k];
            sbkt[p] = bb_[k];
        }
    }
    __syncthreads();
    for (int i = t; i < lim; i += 256) {
        int b = sbkt[i];
        int gpos = basep[b] + (i - ex[b]);
        if (gpos < BCAP) bdata[(size_t)b * BCAP + gpos] = sval[i];
    }
}

// hist + dinv + block-sum (scanA) + degree histogram, fused.
__global__ void __launch_bounds__(256) k_hist2(const unsigned* __restrict__ bdata,
                                               const int* __restrict__ bcnt,
                                               int N, int* __restrict__ deg,
                                               float* __restrict__ dinv,
                                               int* __restrict__ blk_sum,
                                               int* __restrict__ dhist) {
    __shared__ int h[ROWB];
    int t = threadIdx.x, b = blockIdx.x;
    h[t] = 0;
    __syncthreads();
    int cnt = min(bcnt[b], BCAP);
    for (int i = t; i < cnt; i += 256)
        atomicAdd(&h[bdata[(size_t)b * BCAP + i] >> 17], 1);
    __syncthreads();
    int r = b * ROWB + t;
    int d = h[t];
    if (r < N) {
        deg[r] = d;
        dinv[r] = (d > 0) ? rsqrtf((float)d) : 0.0f;
        atomicAdd(&dhist[min(d, 127)], 1);
    }
    __syncthreads();
    for (int off = 128; off > 0; off >>= 1) {
        if (t < off) h[t] += h[t + off];
        __syncthreads();
    }
    if (t == 0) blk_sum[b] = h[0];
}

// Scan blk_sum (exclusive) + scan dhist (exclusive), one block.
__global__ void k_scanB(int* __restrict__ blk_sum, int nb, int* __restrict__ dhist) {
    __shared__ int lds[1024];
    __shared__ int dl[128];
    int t = threadIdx.x;
    int v = (t < nb) ? blk_sum[t] : 0;
    lds[t] = v;
    int dv = 0;
    if (t < 128) { dv = dhist[t]; dl[t] = dv; }
    __syncthreads();
    for (int off = 1; off < 1024; off <<= 1) {
        int val = (t >= off) ? lds[t - off] : 0;
        int dval = (t < 128 && t >= off) ? dl[t - off] : 0;
        __syncthreads();
        lds[t] += val;
        if (t < 128) dl[t] += dval;
        __syncthreads();
    }
    if (t < nb) blk_sum[t] = lds[t] - v;
    if (t < 128) dhist[t] = dl[t] - dv;
}

// Counting-sort scatter: perm[pos] = v, pos from degree-bin cursor.
__global__ void __launch_bounds__(256) k_perm(const int* __restrict__ deg, int N,
                                              int* __restrict__ dhist,
                                              int* __restrict__ perm) {
    int v = blockIdx.x * 256 + threadIdx.x;
    if (v < N) {
        int d = min(deg[v], 127);
        int pos = atomicAdd(&dhist[d], 1);
        perm[pos] = v;
    }
}

// place + scanC fused: local exclusive scan of deg recomputes row_ptr.
__global__ void __launch_bounds__(256) k_place(const unsigned* __restrict__ bdata,
                                               const int* __restrict__ bcnt,
                                               const int* __restrict__ deg,
                                               const int* __restrict__ blk_sum,
                                               int N, int E,
                                               int* __restrict__ row_ptr,
                                               int* __restrict__ sdst) {
    __shared__ int cur[ROWB];
    __shared__ int sc[ROWB];
    __shared__ int staged[BCAP];
    int t = threadIdx.x, b = blockIdx.x;
    int r = b * ROWB + t;
    int d = (r < N) ? deg[r] : 0;
    sc[t] = d;
    __syncthreads();
    for (int off = 1; off < ROWB; off <<= 1) {
        int val = (t >= off) ? sc[t - off] : 0;
        __syncthreads();
        sc[t] += val;
        __syncthreads();
    }
    int excl = sc[t] - d;
    int rbase = blk_sum[b];
    if (r < N) row_ptr[r] = rbase + excl;
    if (b == gridDim.x - 1 && t == ROWB - 1) row_ptr[N] = E;
    cur[t] = excl;
    __syncthreads();
    int cnt = min(bcnt[b], BCAP);
    for (int i = t; i < cnt; i += 256) {
        unsigned val = bdata[(size_t)b * BCAP + i];
        int p = atomicAdd(&cur[val >> 17], 1);
        staged[p] = (int)(val & 0x1FFFFu);
    }
    __syncthreads();
    for (int i = t; i < cnt; i += 256) sdst[rbase + i] = staged[i];
}

// MFMA dense, layer 1. 128 nodes/block, 512 threads = 8 waves, each wave owns
// one 16-row M-tile x 12 N-tiles (192 cols = D | B | C), K=64 in 2 steps of
// v_mfma_f32_16x16x32_f16. All outputs f16: D16 (=x@(W0-W2)+b1, pitch 64),
// B16 (=x@W1, unscaled), C16 (=dinv*(x@W2)).
__global__ void __launch_bounds__(512) k_dense3(const float* __restrict__ x,
                                                const unsigned short* __restrict__ wt1,
                                                const float* __restrict__ b1,
                                                const float* __restrict__ dinv,
                                                int N,
                                                unsigned short* __restrict__ B16,
                                                unsigned short* __restrict__ C16,
                                                unsigned short* __restrict__ D16) {
    __shared__ unsigned short lds[20480] __attribute__((aligned(16)));  // x:[0,8192) W:[8192,20480)
    __shared__ float sb[64];
    int t = threadIdx.x;
    int v0 = blockIdx.x * 128;
    {
        const uint4* src = (const uint4*)wt1;
        uint4* dst = (uint4*)&lds[8192];
        for (int i = t; i < 1536; i += 512) dst[i] = src[i];
    }
    if (t < 64) sb[t] = b1[t];
    {
        int row = t >> 2, c0 = (t & 3) << 4;
        int v = min(v0 + row, N - 1);
        const float* xp = x + (size_t)v * 64 + c0;
        float4 f0 = *(const float4*)xp;
        float4 f1 = *(const float4*)(xp + 4);
        float4 f2 = *(const float4*)(xp + 8);
        float4 f3 = *(const float4*)(xp + 12);
        int key = row & 7;
        int s0 = c0 >> 3;
        f16x8 h0, h1;
        h0[0] = (_Float16)f0.x; h0[1] = (_Float16)f0.y;
        h0[2] = (_Float16)f0.z; h0[3] = (_Float16)f0.w;
        h0[4] = (_Float16)f1.x; h0[5] = (_Float16)f1.y;
        h0[6] = (_Float16)f1.z; h0[7] = (_Float16)f1.w;
        h1[0] = (_Float16)f2.x; h1[1] = (_Float16)f2.y;
        h1[2] = (_Float16)f2.z; h1[3] = (_Float16)f2.w;
        h1[4] = (_Float16)f3.x; h1[5] = (_Float16)f3.y;
        h1[6] = (_Float16)f3.z; h1[7] = (_Float16)f3.w;
        *(f16x8*)&lds[row * 64 + ((s0 ^ key) << 3)] = h0;
        *(f16x8*)&lds[row * 64 + (((s0 + 1) ^ key) << 3)] = h1;
    }
    __syncthreads();

    int w = t >> 6, l = t & 63;
    int lr = l & 15, lk = l >> 4;
    int key = lr & 7;
    int arow = w * 16 + lr;
    f16x8 a0 = *(const f16x8*)&lds[arow * 64 + (((0 + lk) ^ key) << 3)];
    f16x8 a1 = *(const f16x8*)&lds[arow * 64 + (((4 + lk) ^ key) << 3)];
    f32x4 acc[12];
#pragma unroll
    for (int i = 0; i < 12; ++i) acc[i] = (f32x4){0.0f, 0.0f, 0.0f, 0.0f};
#pragma unroll
    for (int nt = 0; nt < 12; ++nt) {
        int bc = nt * 16 + lr;
        const unsigned short* wb = &lds[8192 + bc * 64];
        f16x8 b0 = *(const f16x8*)&wb[((0 + lk) ^ key) << 3];
        f16x8 b1v = *(const f16x8*)&wb[((4 + lk) ^ key) << 3];
        acc[nt] = __builtin_amdgcn_mfma_f32_16x16x32_f16(a0, b0, acc[nt], 0, 0, 0);
        acc[nt] = __builtin_amdgcn_mfma_f32_16x16x32_f16(a1, b1v, acc[nt], 0, 0, 0);
    }
    float4 dv4 = *(const float4*)&dinv[v0 + w * 16 + lk * 4];
    float dsc[4] = {dv4.x, dv4.y, dv4.z, dv4.w};
    __syncthreads();
    // Phase 1: D = acc[0..3]+b1 -> f16 [128][64] in lds
#pragma unroll
    for (int nt = 0; nt < 4; ++nt) {
        int col = nt * 16 + lr;
        float bv = sb[col];
#pragma unroll
        for (int r = 0; r < 4; ++r) {
            int vloc = w * 16 + lk * 4 + r;
            lds[vloc * 64 + col] = f2h(acc[nt][r] + bv);
        }
    }
    __syncthreads();
#pragma unroll
    for (int q = 0; q < 2; ++q) {
        int i = q * 512 + t;          // 16B chunk id, 0..1023
        int row = i >> 3, ch = i & 7;
        int v = v0 + row;
        if (v < N) *(uint4*)(D16 + (size_t)v * 64 + ch * 8) = ((const uint4*)lds)[i];
    }
    __syncthreads();
    // Phase 2: B16 (unscaled) || C16 (dinv-scaled) -> f16 [128][128] in lds
#pragma unroll
    for (int nt = 4; nt < 8; ++nt) {
        int col = (nt - 4) * 16 + lr;
#pragma unroll
        for (int r = 0; r < 4; ++r) {
            int vloc = w * 16 + lk * 4 + r;
            lds[vloc * 128 + col] = f2h(acc[nt][r]);
        }
    }
#pragma unroll
    for (int nt = 8; nt < 12; ++nt) {
        int col = (nt - 4) * 16 + lr;
#pragma unroll
        for (int r = 0; r < 4; ++r) {
            int vloc = w * 16 + lk * 4 + r;
            lds[vloc * 128 + col] = f2h(acc[nt][r] * dsc[r]);
        }
    }
    __syncthreads();
#pragma unroll
    for (int q = 0; q < 4; ++q) {
        int i = q * 512 + t;          // 16B chunk id, 0..2047
        int row = i >> 4, ch = i & 15;
        int v = v0 + row;
        if (v < N) {
            uint4 val = *(const uint4*)&lds[i * 8];
            unsigned short* dst = (ch < 8)
                ? (B16 + (size_t)v * 64 + ch * 8)
                : (C16 + (size_t)v * 64 + (ch - 8) * 8);
            *(uint4*)dst = val;
        }
    }
}

// MFMA dense, layer 2. 128 nodes/block, 512 threads. H read as f16 (C16h).
// nt0,1 -> P0 f32 pitch 32 (D0=H@(W2[0]-W2[2]), direct stores);
// nt2,3 -> P1 f16 pitch 32 (D1=H@W2[1]); nt4,5 -> D2=dinv*(H@W2[2]) f16 pitch 32.
__global__ void __launch_bounds__(512) k_dense3b(const unsigned short* __restrict__ wt2,
                                                 const float* __restrict__ dinv,
                                                 int N,
                                                 unsigned short* __restrict__ B16,
                                                 const unsigned short* __restrict__ C16h,
                                                 float* __restrict__ P0,
                                                 unsigned short* __restrict__ P1h) {
    __shared__ unsigned short lds[14336] __attribute__((aligned(16)));  // x:[0,8192) W:[8192,14336)
    int t = threadIdx.x;
    int v0 = blockIdx.x * 128;
    {
        const uint4* src = (const uint4*)wt2;
        uint4* dst = (uint4*)&lds[8192];
        for (int i = t; i < 768; i += 512) dst[i] = src[i];
    }
    {
        int row = t >> 2, s0 = (t & 3) * 2;
        int v = min(v0 + row, N - 1);
        const uint4* cp = (const uint4*)(C16h + (size_t)v * 64);
        uint4 u0 = cp[s0];
        uint4 u1 = cp[s0 + 1];
        int key = row & 7;
        *(uint4*)&lds[row * 64 + ((s0 ^ key) << 3)] = u0;
        *(uint4*)&lds[row * 64 + (((s0 + 1) ^ key) << 3)] = u1;
    }
    __syncthreads();

    int w = t >> 6, l = t & 63;
    int lr = l & 15, lk = l >> 4;
    int key = lr & 7;
    int arow = w * 16 + lr;
    f16x8 a0 = *(const f16x8*)&lds[arow * 64 + (((0 + lk) ^ key) << 3)];
    f16x8 a1 = *(const f16x8*)&lds[arow * 64 + (((4 + lk) ^ key) << 3)];
    f32x4 acc[6];
#pragma unroll
    for (int i = 0; i < 6; ++i) acc[i] = (f32x4){0.0f, 0.0f, 0.0f, 0.0f};
#pragma unroll
    for (int nt = 0; nt < 6; ++nt) {
        int bc = nt * 16 + lr;
        const unsigned short* wb = &lds[8192 + bc * 64];
        f16x8 b0 = *(const f16x8*)&wb[((0 + lk) ^ key) << 3];
        f16x8 b1v = *(const f16x8*)&wb[((4 + lk) ^ key) << 3];
        acc[nt] = __builtin_amdgcn_mfma_f32_16x16x32_f16(a0, b0, acc[nt], 0, 0, 0);
        acc[nt] = __builtin_amdgcn_mfma_f32_16x16x32_f16(a1, b1v, acc[nt], 0, 0, 0);
    }
    float4 dv4 = *(const float4*)&dinv[v0 + w * 16 + lk * 4];
    float dsc[4] = {dv4.x, dv4.y, dv4.z, dv4.w};
    // P0 f32 direct stores
#pragma unroll
    for (int nt = 0; nt < 2; ++nt) {
        int col = nt * 16 + lr;
#pragma unroll
        for (int r = 0; r < 4; ++r) {
            int v = v0 + w * 16 + lk * 4 + r;
            if (v < N) P0[(size_t)v * 32 + col] = acc[nt][r];
        }
    }
    __syncthreads();
    // repack P1 (cols 0..31) || D2-scaled (cols 32..63) as f16 [128][64]
#pragma unroll
    for (int nt = 2; nt < 4; ++nt) {
        int col = (nt - 2) * 16 + lr;
#pragma unroll
        for (int r = 0; r < 4; ++r) {
            int vloc = w * 16 + lk * 4 + r;
            lds[vloc * 64 + col] = f2h(acc[nt][r]);
        }
    }
#pragma unroll
    for (int nt = 4; nt < 6; ++nt) {
        int col = (nt - 2) * 16 + lr;
#pragma unroll
        for (int r = 0; r < 4; ++r) {
            int vloc = w * 16 + lk * 4 + r;
            lds[vloc * 64 + col] = f2h(acc[nt][r] * dsc[r]);
        }
    }
    __syncthreads();
#pragma unroll
    for (int q = 0; q < 2; ++q) {
        int i = q * 512 + t;          // 16B chunk id, 0..1023
        int row = i >> 3, ch = i & 7;
        int v = v0 + row;
        if (v < N) {
            uint4 val = ((const uint4*)lds)[i];
            unsigned short* dst = (ch < 4)
                ? (P1h + (size_t)v * 32 + ch * 8)
                : (B16 + (size_t)v * 32 + (ch - 4) * 8);
            *(uint4*)dst = val;
        }
    }
}

// Multi-node gather, packed f16: LPN lanes per node, NG = LPN/(PITCH/8)
// edge-groups. 4-deep unrolled (4 independent sdst+row loads in flight).
// Sources pre-scaled by dinv[c]; accumulate with v_pk_add_f16; single-stage
// packed xor-reduce; final convert to f32.
template <int PITCH, int LPN>
__device__ __forceinline__ void gatherH(const unsigned short* __restrict__ src,
                                        const int* __restrict__ sdst,
                                        int beg, int end, int grp, int fl,
                                        float a[8]) {
    constexpr int NG = LPN / (PITCH / 8);
    f16x8 acc;
#pragma unroll
    for (int q = 0; q < 8; ++q) acc[q] = (_Float16)0;
    int e = beg + grp;
    for (; e + 3 * NG < end; e += 4 * NG) {
        int c0 = sdst[e];
        int c1 = sdst[e + NG];
        int c2 = sdst[e + 2 * NG];
        int c3 = sdst[e + 3 * NG];
        f16x8 r0 = *(const f16x8*)(src + (size_t)c0 * PITCH + 8 * fl);
        f16x8 r1 = *(const f16x8*)(src + (size_t)c1 * PITCH + 8 * fl);
        f16x8 r2 = *(const f16x8*)(src + (size_t)c2 * PITCH + 8 * fl);
        f16x8 r3 = *(const f16x8*)(src + (size_t)c3 * PITCH + 8 * fl);
        acc = acc + r0;
        acc = acc + r1;
        acc = acc + r2;
        acc = acc + r3;
    }
    for (; e < end; e += NG) {
        int c = sdst[e];
        f16x8 r = *(const f16x8*)(src + (size_t)c * PITCH + 8 * fl);
        acc = acc + r;
    }
#pragma unroll
    for (int m = PITCH / 8; m < LPN; m <<= 1) {
        union { f16x8 h; int i4[4]; } u;
        u.h = acc;
#pragma unroll
        for (int q = 0; q < 4; ++q) u.i4[q] = __shfl_xor(u.i4[q], m);
        acc = acc + u.h;
    }
#pragma unroll
    for (int q = 0; q < 8; ++q) a[q] = (float)acc[q];
}

// Gather 1: B16[v] = f16( dinv[v] * (B16[v] - 2*dinv[v]*sum C16'[c]) )
// 16 lanes/node (4 nodes/wave), degree-sorted via perm.
__global__ void __launch_bounds__(BLK) k_gath1(const unsigned short* __restrict__ C16,
                                               unsigned short* __restrict__ B16,
                                               const float* __restrict__ dinv,
                                               const int* __restrict__ row_ptr,
                                               const int* __restrict__ sdst,
                                               const int* __restrict__ perm,
                                               int N) {
    int vidx = blockIdx.x * 16 + (threadIdx.x >> 4);
    if (vidx >= N) return;
    int v = perm[vidx];
    int ln = threadIdx.x & 15;
    int grp = ln >> 3, fl = ln & 7;
    float a[8];
    gatherH<64, 16>(C16, sdst, row_ptr[v], row_ptr[v + 1], grp, fl, a);
    if (grp == 0) {
        float di = dinv[v];
        float dv = -2.0f * di;
        unsigned short* p = B16 + (size_t)v * 64 + 8 * fl;
        f16x8 b = *(const f16x8*)p;
        uint4 o;
        o.x = pack2h(di * fmaf(dv, a[0], (float)b[0]), di * fmaf(dv, a[1], (float)b[1]));
        o.y = pack2h(di * fmaf(dv, a[2], (float)b[2]), di * fmaf(dv, a[3], (float)b[3]));
        o.z = pack2h(di * fmaf(dv, a[4], (float)b[4]), di * fmaf(dv, a[5], (float)b[5]));
        o.w = pack2h(di * fmaf(dv, a[6], (float)b[6]), di * fmaf(dv, a[7], (float)b[7]));
        *(uint4*)p = o;
    }
}

// Gather 2: C16h[v] (f16 H) = dropout(relu(D16[v] - dinv[v]*sum B16'[c])).
// 16 lanes/node, degree-sorted.
__global__ void __launch_bounds__(BLK) k_gath2(const unsigned short* __restrict__ D16,
                                               const unsigned short* __restrict__ B16,
                                               unsigned short* __restrict__ C16h,
                                               const unsigned long long* __restrict__ dmask,
                                               const float* __restrict__ dinv,
                                               const int* __restrict__ row_ptr,
                                               const int* __restrict__ sdst,
                                               const int* __restrict__ perm,
                                               int N) {
    int vidx = blockIdx.x * 16 + (threadIdx.x >> 4);
    if (vidx >= N) return;
    int v = perm[vidx];
    int ln = threadIdx.x & 15;
    int grp = ln >> 3, fl = ln & 7;
    float a[8];
    gatherH<64, 16>(B16, sdst, row_ptr[v], row_ptr[v + 1], grp, fl, a);
    if (grp == 0) {
        unsigned long long dm = dmask[v] >> (8 * fl);
        float dv = -dinv[v];
        f16x8 d = *(const f16x8*)(D16 + (size_t)v * 64 + 8 * fl);
        float o[8];
#pragma unroll
        for (int k = 0; k < 8; ++k)
            o[k] = fmaxf(fmaf(dv, a[k], (float)d[k]), 0.0f);
#pragma unroll
        for (int k = 0; k < 8; ++k)
            o[k] = ((dm >> k) & 1ull) ? 0.0f : o[k] * 2.0f;
        uint4 oo;
        oo.x = pack2h(o[0], o[1]); oo.y = pack2h(o[2], o[3]);
        oo.z = pack2h(o[4], o[5]); oo.w = pack2h(o[6], o[7]);
        *(uint4*)(C16h + (size_t)v * 64 + 8 * fl) = oo;
    }
}

// Gather 3: R16[v] = f16( dinv[v] * (P1[v] - 2*dinv[v]*sum D2'[c]) )
// 8 lanes/node (8 nodes/wave), degree-sorted.
__global__ void __launch_bounds__(BLK) k_gath3(const unsigned short* __restrict__ B16,
                                               const unsigned short* __restrict__ P1h,
                                               unsigned short* __restrict__ R16,
                                               const float* __restrict__ dinv,
                                               const int* __restrict__ row_ptr,
                                               const int* __restrict__ sdst,
                                               const int* __restrict__ perm,
                                               int N) {
    int vidx = blockIdx.x * 32 + (threadIdx.x >> 3);
    if (vidx >= N) return;
    int v = perm[vidx];
    int ln = threadIdx.x & 7;
    int grp = ln >> 2, fl = ln & 3;
    float a[8];
    gatherH<32, 8>(B16, sdst, row_ptr[v], row_ptr[v + 1], grp, fl, a);
    if (grp == 0) {
        float di = dinv[v];
        float dv = -2.0f * di;
        f16x8 d = *(const f16x8*)(P1h + (size_t)v * 32 + 8 * fl);
        uint4 o;
        o.x = pack2h(di * fmaf(dv, a[0], (float)d[0]), di * fmaf(dv, a[1], (float)d[1]));
        o.y = pack2h(di * fmaf(dv, a[2], (float)d[2]), di * fmaf(dv, a[3], (float)d[3]));
        o.z = pack2h(di * fmaf(dv, a[4], (float)d[4]), di * fmaf(dv, a[5], (float)d[5]));
        o.w = pack2h(di * fmaf(dv, a[6], (float)d[6]), di * fmaf(dv, a[7], (float)d[7]));
        *(uint4*)(R16 + (size_t)v * 32 + 8 * fl) = o;
    }
}

// Gather 4: out = log_softmax(P0 + b2 - dinv[v]*sum R16'[c]). 8 lanes/node,
// degree-sorted.
__global__ void __launch_bounds__(BLK) k_gath4(const unsigned short* __restrict__ R16,
                                               const float* __restrict__ P0,
                                               const float* __restrict__ dinv,
                                               const int* __restrict__ row_ptr,
                                               const int* __restrict__ sdst,
                                               const int* __restrict__ perm,
                                               const float* __restrict__ b2,
                                               int N, float* __restrict__ out) {
    int vidx = blockIdx.x * 32 + (threadIdx.x >> 3);
    if (vidx >= N) return;
    int v = perm[vidx];
    int ln = threadIdx.x & 7;
    int grp = ln >> 2, fl = ln & 3;
    float a[8];
    gatherH<32, 8>(R16, sdst, row_ptr[v], row_ptr[v + 1], grp, fl, a);
    float dv = -dinv[v];
    const float* dp = P0 + (size_t)v * 32 + 8 * fl;
    float4 dA = *(const float4*)dp;
    float4 dB = *(const float4*)(dp + 4);
    const float* bp = b2 + 8 * fl;
    float4 bA = *(const float4*)bp;
    float4 bB = *(const float4*)(bp + 4);
    float o[8];
    o[0] = fmaf(dv, a[0], dA.x + bA.x);
    o[1] = fmaf(dv, a[1], dA.y + bA.y);
    o[2] = fmaf(dv, a[2], dA.z + bA.z);
    o[3] = fmaf(dv, a[3], dA.w + bA.w);
    o[4] = fmaf(dv, a[4], dB.x + bB.x);
    o[5] = fmaf(dv, a[5], dB.y + bB.y);
    o[6] = fmaf(dv, a[6], dB.z + bB.z);
    o[7] = fmaf(dv, a[7], dB.w + bB.w);
    float m = o[0];
#pragma unroll
    for (int k = 1; k < 8; ++k) m = fmaxf(m, o[k]);
    m = fmaxf(m, __shfl_xor(m, 1));
    m = fmaxf(m, __shfl_xor(m, 2));
    float s = 0.0f;
#pragma unroll
    for (int k = 0; k < 8; ++k) s += __expf(o[k] - m);
    s += __shfl_xor(s, 1);
    s += __shfl_xor(s, 2);
    float lse = m + __logf(s);
    if (grp == 0) {
        float* op = out + (size_t)v * 32 + 8 * fl;
        *(float4*)op = make_float4(o[0] - lse, o[1] - lse, o[2] - lse, o[3] - lse);
        *(float4*)(op + 4) = make_float4(o[4] - lse, o[5] - lse, o[6] - lse, o[7] - lse);
    }
}

extern "C" void kernel_launch(void* const* d_in, const int* in_sizes, int n_in,
                              void* d_out, int out_size, void* d_ws, size_t ws_size,
                              hipStream_t stream) {
    const float* x  = (const float*)d_in[0];
    const int* ei   = (const int*)d_in[1];
    const float* W1 = (const float*)d_in[2];
    const float* b1 = (const float*)d_in[3];
    const float* W2 = (const float*)d_in[4];
    const float* b2 = (const float*)d_in[5];
    float* out = (float*)d_out;

    const int N = in_sizes[0] / 64;
    const int E = in_sizes[1] / 2;
    const int NB = (N + ROWB - 1) >> RB_SHIFT;

    char* ws = (char*)d_ws;
    size_t off = 0;
    auto alloc = [&](size_t bytes) -> void* {
        void* p = ws + off;
        off = (off + bytes + 511) & ~(size_t)511;
        return p;
    };
    int*      flags   = (int*)alloc(16);
    int*      deg     = (int*)alloc((size_t)N * 4);
    float*    dinv    = (float*)alloc((size_t)N * 4);
    int*      row_ptr = (int*)alloc(((size_t)N + 1) * 4);
    int*      blk_sum = (int*)alloc(4096);
    int*      bcnt    = (int*)alloc((size_t)NB * 4 + 512);  // + dhist[128]
    int*      dhist   = bcnt + NB;
    int*      perm    = (int*)alloc((size_t)N * 4);
    // Region shared over time: bdata (preproc) -> D16 (layer1 f16, N*64) ->
    // P0 (f32 N*32) || P1h (f16 N*32), written by dense3b after D16 is dead.
    size_t dbytes = (size_t)N * 64 * 4;
    size_t bdbytes = (size_t)NB * BCAP * 4;
    unsigned* bdata = (unsigned*)alloc(dbytes > bdbytes ? dbytes : bdbytes);
    unsigned short* D16 = (unsigned short*)bdata;
    float*    P0    = (float*)bdata;
    unsigned short* P1h = (unsigned short*)((char*)bdata + (size_t)N * 32 * 4);
    int*      sdst  = (int*)alloc((size_t)E * 4);
    unsigned short* C16h = (unsigned short*)alloc((size_t)N * 64 * 2);  // H (f16)
    unsigned short* B16 = (unsigned short*)alloc((size_t)N * 64 * 2);
    // C16 (layer-1 gather source, dead after gath1) shares with R16 (layer-2).
    unsigned short* C16 = (unsigned short*)alloc((size_t)N * 64 * 2);
    unsigned short* R16 = C16;
    unsigned long long* dmask = (unsigned long long*)alloc((size_t)N * 8);
    unsigned short* wt1 = (unsigned short*)alloc(12288 * 2);
    unsigned short* wt2 = (unsigned short*)alloc(6144 * 2);

    hipMemsetAsync(bcnt, 0, (size_t)NB * 4 + 512, stream);

    const int gW16 = (N + 15) / 16;
    const int gW32 = (N + 31) / 32;
    const int gDM = (N + 127) / 128;
    const int gN = (N + 255) / 256;
    const int nb = NB;
    const int gBin = (E + CHUNK - 1) / CHUNK;
    const int gDrop = (N * 64 + 255) / 256;

    k_init<<<gDrop + 1 + 72, 256, 0, stream>>>(N * 64, ei, W1, W2, flags, dmask,
                                               wt1, wt2, gDrop);
    k_bin<<<gBin, 256, 0, stream>>>(ei, E, flags, bcnt, bdata, NB);
    k_hist2<<<NB, 256, 0, stream>>>(bdata, bcnt, N, deg, dinv, blk_sum, dhist);
    k_scanB<<<1, 1024, 0, stream>>>(blk_sum, nb, dhist);
    k_perm<<<gN, 256, 0, stream>>>(deg, N, dhist, perm);
    k_place<<<NB, 256, 0, stream>>>(bdata, bcnt, deg, blk_sum, N, E, row_ptr, sdst);

    // Layer 1: B16=f16(x@W1[1]), C16=f16(dinv*(x@W1[2])), D16=f16(x@(W1[0]-W1[2])+b1);
    // B16 = dinv*(B16 - 2*dinv*S'(C16)); H = drop(relu(D16 - dinv*S'(B16)))
    k_dense3<<<gDM, 512, 0, stream>>>(x, wt1, b1, dinv, N, B16, C16, D16);
    k_gath1<<<gW16, BLK, 0, stream>>>(C16, B16, dinv, row_ptr, sdst, perm, N);
    k_gath2<<<gW16, BLK, 0, stream>>>(D16, B16, C16h, dmask, dinv, row_ptr, sdst, perm, N);

    // Layer 2: D0->P0 f32, D1->P1h f16 (pitch 32); D2 pre-scaled f16 in B16 (pitch 32);
    // R16 = dinv*(P1 - 2*dinv*S'(D2)); out = lsm(P0 + b2 - dinv*S'(R16))
    k_dense3b<<<gDM, 512, 0, stream>>>(wt2, dinv, N, B16, C16h, P0, P1h);
    k_gath3<<<gW32, BLK, 0, stream>>>(B16, P1h, R16, dinv, row_ptr, sdst, perm, N);
    k_gath4<<<gW32, BLK, 0, stream>>>(R16, P0, dinv, row_ptr, sdst, perm, b2, N, out);
}

// Round 7
// 295.677 us; speedup vs baseline: 2.9608x; 2.9608x over previous
//
#include <hip/hip_runtime.h>

// ChebNet K=3, W-first form: ChebConv(H) = H@(W0-W2) + S·(H@W1 + 2·S·(H@W2)).
// Round 19: fix round-18's global-atomic contention -- dhist updates in
// k_hist2 and k_perm now aggregate per-block in LDS first, then emit ONE
// global atomic per bin per block (was: one per node -> 12k serialized RMWs
// on the hottest bin = 293us in k_hist2 alone). Degree-balanced gather
// permutation kept (4 nodes/wave of ~equal degree).

static constexpr int BLK = 256;
static constexpr int ROWB = 256;
static constexpr int RB_SHIFT = 8;
static constexpr int BCAP = 6144;
static constexpr int CHUNK = 8192;

typedef _Float16 f16x8 __attribute__((ext_vector_type(8)));
typedef _Float16 f16x2 __attribute__((ext_vector_type(2)));
typedef float f32x4 __attribute__((ext_vector_type(4)));

__device__ __forceinline__ unsigned rotl32(unsigned x, int r) {
    return (x << r) | (x >> (32 - r));
}

// JAX partitionable threefry word for element i:
// (b1,b2) = threefry2x32(key=(0,42), counter=(0,i)); word = b1 ^ b2.
__device__ __forceinline__ unsigned tf_word(unsigned i) {
    const unsigned ks0 = 0u;
    const unsigned ks1 = 42u;
    const unsigned ks2 = 0u ^ 42u ^ 0x1BD11BDAu;
    unsigned x0 = 0u + ks0;
    unsigned x1 = i + ks1;
#define TF_RND(r) { x0 += x1; x1 = rotl32(x1, (r)); x1 ^= x0; }
    TF_RND(13) TF_RND(15) TF_RND(26) TF_RND(6)
    x0 += ks1; x1 += ks2 + 1u;
    TF_RND(17) TF_RND(29) TF_RND(16) TF_RND(24)
    x0 += ks2; x1 += ks0 + 2u;
    TF_RND(13) TF_RND(15) TF_RND(26) TF_RND(6)
    x0 += ks0; x1 += ks1 + 3u;
    TF_RND(17) TF_RND(29) TF_RND(16) TF_RND(24)
    x0 += ks1; x1 += ks2 + 4u;
    TF_RND(13) TF_RND(15) TF_RND(26) TF_RND(6)
    x0 += ks2; x1 += ks0 + 5u;
#undef TF_RND
    return x0 ^ x1;
}

// f16 pack/unpack
__device__ __forceinline__ unsigned short f2h(float f) {
    union { _Float16 h; unsigned short u; } c; c.h = (_Float16)f; return c.u;
}
__device__ __forceinline__ unsigned pack2h(float a, float b) {
    union { f16x2 h; unsigned u; } c;
    c.h[0] = (_Float16)a; c.h[1] = (_Float16)b;
    return c.u;
}

// Fused init: blocks [0,gDrop) dropout mask; block gDrop int64-detect;
// blocks (gDrop, gDrop+72] weight prep (fp16, transposed, pre-XOR-swizzled).
__global__ void __launch_bounds__(256) k_init(int NW, const int* __restrict__ ei,
                                              const float* __restrict__ W1,
                                              const float* __restrict__ W2,
                                              int* __restrict__ flags,
                                              unsigned long long* __restrict__ dmask,
                                              unsigned short* __restrict__ wt1,
                                              unsigned short* __restrict__ wt2,
                                              int gDrop) {
    int b = blockIdx.x;
    int t = threadIdx.x;
    if (b < gDrop) {
        int idx = b * 256 + t;
        unsigned word = (idx < NW) ? tf_word((unsigned)idx) : 0u;
        unsigned long long bal = __ballot(word >> 31);
        if ((t & 63) == 0 && idx < NW) dmask[idx >> 6] = bal;
        return;
    }
    if (b == gDrop) {
        __shared__ int cnt_nz;
        if (t == 0) cnt_nz = 0;
        __syncthreads();
        if (ei[2 * t + 1] != 0) atomicAdd(&cnt_nz, 1);
        __syncthreads();
        if (t == 0) flags[0] = (cnt_nz == 0) ? 1 : 0;
        return;
    }
    int idx = (b - gDrop - 1) * 256 + t;
    if (idx < 12288) {
        int c = idx >> 6, r6 = idx & 63;
        int slot = (r6 >> 3) ^ (c & 7);
        int k = slot * 8 + (r6 & 7);
        float v;
        if (c < 64)       v = W1[k * 64 + c] - W1[8192 + k * 64 + c];
        else if (c < 128) v = W1[4096 + k * 64 + (c - 64)];
        else              v = W1[8192 + k * 64 + (c - 128)];
        wt1[idx] = f2h(v);
    } else {
        int j = idx - 12288;
        int c = j >> 6, r6 = j & 63;
        int slot = (r6 >> 3) ^ (c & 7);
        int k = slot * 8 + (r6 & 7);
        float v;
        if (c < 32)      v = W2[k * 32 + c] - W2[4096 + k * 32 + c];
        else if (c < 64) v = W2[2048 + k * 32 + (c - 32)];
        else             v = W2[4096 + k * 32 + (c - 64)];
        wt2[j] = f2h(v);
    }
}

// Pass 1: bin edges into row-buckets, LDS-staged for coalesced writes.
__global__ void __launch_bounds__(256) k_bin(const int* __restrict__ ei, int E,
                                             const int* __restrict__ flags,
                                             int* __restrict__ bcnt,
                                             unsigned* __restrict__ bdata, int NB) {
    __shared__ unsigned sval[CHUNK];
    __shared__ unsigned short sbkt[CHUNK];
    __shared__ int h[512], ex[512], cur[512], basep[512];
    int t = threadIdx.x;
    int start = blockIdx.x * CHUNK;
    int lim = min(CHUNK, E - start);
    bool i64 = flags[0] != 0;
    h[t] = 0; h[t + 256] = 0;
    __syncthreads();
    unsigned vv[32];
    unsigned short bb_[32];
#pragma unroll
    for (int k = 0; k < 32; ++k) {
        int idx = k * 256 + t;
        int e = start + idx;
        if (idx < lim) {
            int r, c;
            if (i64) { r = ei[2 * e]; c = ei[2 * (E + e)]; }
            else     { r = ei[e];     c = ei[E + e]; }
            int b = r >> RB_SHIFT;
            vv[k] = ((unsigned)(r & (ROWB - 1)) << 17) | (unsigned)c;
            bb_[k] = (unsigned short)b;
            atomicAdd(&h[b], 1);
        } else {
            bb_[k] = 0xFFFF;
        }
    }
    __syncthreads();
    int i0 = t, i1 = t + 256;
    ex[i0] = h[i0]; ex[i1] = h[i1];
    __syncthreads();
    for (int off = 1; off < 512; off <<= 1) {
        int v0 = (i0 >= off) ? ex[i0 - off] : 0;
        int v1 = (i1 >= off) ? ex[i1 - off] : 0;
        __syncthreads();
        ex[i0] += v0; ex[i1] += v1;
        __syncthreads();
    }
    int e0 = ex[i0] - h[i0], e1 = ex[i1] - h[i1];
    __syncthreads();
    ex[i0] = e0; cur[i0] = e0;
    ex[i1] = e1; cur[i1] = e1;
    if (i0 < NB && h[i0] > 0) basep[i0] = atomicAdd(&bcnt[i0], h[i0]);
    if (i1 < NB && h[i1] > 0) basep[i1] = atomicAdd(&bcnt[i1], h[i1]);
    __syncthreads();
#pragma unroll
    for (int k = 0; k < 32; ++k) {
        if (bb_[k] != 0xFFFF) {
            int p = atomicAdd(&cur[bb_[k]], 1);
            sval[p] = vv[k];
            sbkt[p] = bb_[k];
        }
    }
    __syncthreads();
    for (int i = t; i < lim; i += 256) {
        int b = sbkt[i];
        int gpos = basep[b] + (i - ex[b]);
        if (gpos < BCAP) bdata[(size_t)b * BCAP + gpos] = sval[i];
    }
}

// hist + dinv + block-sum + degree histogram (LDS-aggregated), fused.
__global__ void __launch_bounds__(256) k_hist2(const unsigned* __restrict__ bdata,
                                               const int* __restrict__ bcnt,
                                               int N, int* __restrict__ deg,
                                               float* __restrict__ dinv,
                                               int* __restrict__ blk_sum,
                                               int* __restrict__ dhist) {
    __shared__ int h[ROWB];
    __shared__ int dh[128];
    int t = threadIdx.x, b = blockIdx.x;
    h[t] = 0;
    if (t < 128) dh[t] = 0;
    __syncthreads();
    int cnt = min(bcnt[b], BCAP);
    for (int i = t; i < cnt; i += 256)
        atomicAdd(&h[bdata[(size_t)b * BCAP + i] >> 17], 1);
    __syncthreads();
    int r = b * ROWB + t;
    int d = h[t];
    if (r < N) {
        deg[r] = d;
        dinv[r] = (d > 0) ? rsqrtf((float)d) : 0.0f;
        atomicAdd(&dh[min(d, 127)], 1);   // LDS aggregation
    }
    __syncthreads();
    if (t < 128 && dh[t] > 0) atomicAdd(&dhist[t], dh[t]);  // 1 atomic/bin/block
    for (int off = 128; off > 0; off >>= 1) {
        if (t < off) h[t] += h[t + off];
        __syncthreads();
    }
    if (t == 0) blk_sum[b] = h[0];
}

// Scan blk_sum (exclusive) + scan dhist (exclusive), one block.
__global__ void k_scanB(int* __restrict__ blk_sum, int nb, int* __restrict__ dhist) {
    __shared__ int lds[1024];
    __shared__ int dl[128];
    int t = threadIdx.x;
    int v = (t < nb) ? blk_sum[t] : 0;
    lds[t] = v;
    int dv = 0;
    if (t < 128) { dv = dhist[t]; dl[t] = dv; }
    __syncthreads();
    for (int off = 1; off < 1024; off <<= 1) {
        int val = (t >= off) ? lds[t - off] : 0;
        int dval = (t < 128 && t >= off) ? dl[t - off] : 0;
        __syncthreads();
        lds[t] += val;
        if (t < 128) dl[t] += dval;
        __syncthreads();
    }
    if (t < nb) blk_sum[t] = lds[t] - v;
    if (t < 128) dhist[t] = dl[t] - dv;
}

// Counting-sort scatter, LDS-aggregated: block claims per-bin ranges with one
// global atomic per bin, threads place via LDS rank.
__global__ void __launch_bounds__(256) k_perm(const int* __restrict__ deg, int N,
                                              int* __restrict__ dhist,
                                              int* __restrict__ perm) {
    __shared__ int lh[128];
    __shared__ int lbase[128];
    int t = threadIdx.x;
    if (t < 128) lh[t] = 0;
    __syncthreads();
    int v = blockIdx.x * 256 + t;
    int d = 0, rank = 0;
    if (v < N) {
        d = min(deg[v], 127);
        rank = atomicAdd(&lh[d], 1);      // LDS rank
    }
    __syncthreads();
    if (t < 128 && lh[t] > 0) lbase[t] = atomicAdd(&dhist[t], lh[t]);
    __syncthreads();
    if (v < N) perm[lbase[d] + rank] = v;
}

// place + scanC fused: local exclusive scan of deg recomputes row_ptr.
__global__ void __launch_bounds__(256) k_place(const unsigned* __restrict__ bdata,
                                               const int* __restrict__ bcnt,
                                               const int* __restrict__ deg,
                                               const int* __restrict__ blk_sum,
                                               int N, int E,
                                               int* __restrict__ row_ptr,
                                               int* __restrict__ sdst) {
    __shared__ int cur[ROWB];
    __shared__ int sc[ROWB];
    __shared__ int staged[BCAP];
    int t = threadIdx.x, b = blockIdx.x;
    int r = b * ROWB + t;
    int d = (r < N) ? deg[r] : 0;
    sc[t] = d;
    __syncthreads();
    for (int off = 1; off < ROWB; off <<= 1) {
        int val = (t >= off) ? sc[t - off] : 0;
        __syncthreads();
        sc[t] += val;
        __syncthreads();
    }
    int excl = sc[t] - d;
    int rbase = blk_sum[b];
    if (r < N) row_ptr[r] = rbase + excl;
    if (b == gridDim.x - 1 && t == ROWB - 1) row_ptr[N] = E;
    cur[t] = excl;
    __syncthreads();
    int cnt = min(bcnt[b], BCAP);
    for (int i = t; i < cnt; i += 256) {
        unsigned val = bdata[(size_t)b * BCAP + i];
        int p = atomicAdd(&cur[val >> 17], 1);
        staged[p] = (int)(val & 0x1FFFFu);
    }
    __syncthreads();
    for (int i = t; i < cnt; i += 256) sdst[rbase + i] = staged[i];
}

// MFMA dense, layer 1. 128 nodes/block, 512 threads = 8 waves, each wave owns
// one 16-row M-tile x 12 N-tiles (192 cols = D | B | C), K=64 in 2 steps of
// v_mfma_f32_16x16x32_f16. All outputs f16: D16 (=x@(W0-W2)+b1, pitch 64),
// B16 (=x@W1, unscaled), C16 (=dinv*(x@W2)).
__global__ void __launch_bounds__(512) k_dense3(const float* __restrict__ x,
                                                const unsigned short* __restrict__ wt1,
                                                const float* __restrict__ b1,
                                                const float* __restrict__ dinv,
                                                int N,
                                                unsigned short* __restrict__ B16,
                                                unsigned short* __restrict__ C16,
                                                unsigned short* __restrict__ D16) {
    __shared__ unsigned short lds[20480] __attribute__((aligned(16)));  // x:[0,8192) W:[8192,20480)
    __shared__ float sb[64];
    int t = threadIdx.x;
    int v0 = blockIdx.x * 128;
    {
        const uint4* src = (const uint4*)wt1;
        uint4* dst = (uint4*)&lds[8192];
        for (int i = t; i < 1536; i += 512) dst[i] = src[i];
    }
    if (t < 64) sb[t] = b1[t];
    {
        int row = t >> 2, c0 = (t & 3) << 4;
        int v = min(v0 + row, N - 1);
        const float* xp = x + (size_t)v * 64 + c0;
        float4 f0 = *(const float4*)xp;
        float4 f1 = *(const float4*)(xp + 4);
        float4 f2 = *(const float4*)(xp + 8);
        float4 f3 = *(const float4*)(xp + 12);
        int key = row & 7;
        int s0 = c0 >> 3;
        f16x8 h0, h1;
        h0[0] = (_Float16)f0.x; h0[1] = (_Float16)f0.y;
        h0[2] = (_Float16)f0.z; h0[3] = (_Float16)f0.w;
        h0[4] = (_Float16)f1.x; h0[5] = (_Float16)f1.y;
        h0[6] = (_Float16)f1.z; h0[7] = (_Float16)f1.w;
        h1[0] = (_Float16)f2.x; h1[1] = (_Float16)f2.y;
        h1[2] = (_Float16)f2.z; h1[3] = (_Float16)f2.w;
        h1[4] = (_Float16)f3.x; h1[5] = (_Float16)f3.y;
        h1[6] = (_Float16)f3.z; h1[7] = (_Float16)f3.w;
        *(f16x8*)&lds[row * 64 + ((s0 ^ key) << 3)] = h0;
        *(f16x8*)&lds[row * 64 + (((s0 + 1) ^ key) << 3)] = h1;
    }
    __syncthreads();

    int w = t >> 6, l = t & 63;
    int lr = l & 15, lk = l >> 4;
    int key = lr & 7;
    int arow = w * 16 + lr;
    f16x8 a0 = *(const f16x8*)&lds[arow * 64 + (((0 + lk) ^ key) << 3)];
    f16x8 a1 = *(const f16x8*)&lds[arow * 64 + (((4 + lk) ^ key) << 3)];
    f32x4 acc[12];
#pragma unroll
    for (int i = 0; i < 12; ++i) acc[i] = (f32x4){0.0f, 0.0f, 0.0f, 0.0f};
#pragma unroll
    for (int nt = 0; nt < 12; ++nt) {
        int bc = nt * 16 + lr;
        const unsigned short* wb = &lds[8192 + bc * 64];
        f16x8 b0 = *(const f16x8*)&wb[((0 + lk) ^ key) << 3];
        f16x8 b1v = *(const f16x8*)&wb[((4 + lk) ^ key) << 3];
        acc[nt] = __builtin_amdgcn_mfma_f32_16x16x32_f16(a0, b0, acc[nt], 0, 0, 0);
        acc[nt] = __builtin_amdgcn_mfma_f32_16x16x32_f16(a1, b1v, acc[nt], 0, 0, 0);
    }
    float4 dv4 = *(const float4*)&dinv[v0 + w * 16 + lk * 4];
    float dsc[4] = {dv4.x, dv4.y, dv4.z, dv4.w};
    __syncthreads();
    // Phase 1: D = acc[0..3]+b1 -> f16 [128][64] in lds
#pragma unroll
    for (int nt = 0; nt < 4; ++nt) {
        int col = nt * 16 + lr;
        float bv = sb[col];
#pragma unroll
        for (int r = 0; r < 4; ++r) {
            int vloc = w * 16 + lk * 4 + r;
            lds[vloc * 64 + col] = f2h(acc[nt][r] + bv);
        }
    }
    __syncthreads();
#pragma unroll
    for (int q = 0; q < 2; ++q) {
        int i = q * 512 + t;          // 16B chunk id, 0..1023
        int row = i >> 3, ch = i & 7;
        int v = v0 + row;
        if (v < N) *(uint4*)(D16 + (size_t)v * 64 + ch * 8) = ((const uint4*)lds)[i];
    }
    __syncthreads();
    // Phase 2: B16 (unscaled) || C16 (dinv-scaled) -> f16 [128][128] in lds
#pragma unroll
    for (int nt = 4; nt < 8; ++nt) {
        int col = (nt - 4) * 16 + lr;
#pragma unroll
        for (int r = 0; r < 4; ++r) {
            int vloc = w * 16 + lk * 4 + r;
            lds[vloc * 128 + col] = f2h(acc[nt][r]);
        }
    }
#pragma unroll
    for (int nt = 8; nt < 12; ++nt) {
        int col = (nt - 4) * 16 + lr;
#pragma unroll
        for (int r = 0; r < 4; ++r) {
            int vloc = w * 16 + lk * 4 + r;
            lds[vloc * 128 + col] = f2h(acc[nt][r] * dsc[r]);
        }
    }
    __syncthreads();
#pragma unroll
    for (int q = 0; q < 4; ++q) {
        int i = q * 512 + t;          // 16B chunk id, 0..2047
        int row = i >> 4, ch = i & 15;
        int v = v0 + row;
        if (v < N) {
            uint4 val = *(const uint4*)&lds[i * 8];
            unsigned short* dst = (ch < 8)
                ? (B16 + (size_t)v * 64 + ch * 8)
                : (C16 + (size_t)v * 64 + (ch - 8) * 8);
            *(uint4*)dst = val;
        }
    }
}

// MFMA dense, layer 2. 128 nodes/block, 512 threads. H read as f16 (C16h).
// nt0,1 -> P0 f32 pitch 32 (D0=H@(W2[0]-W2[2]), direct stores);
// nt2,3 -> P1 f16 pitch 32 (D1=H@W2[1]); nt4,5 -> D2=dinv*(H@W2[2]) f16 pitch 32.
__global__ void __launch_bounds__(512) k_dense3b(const unsigned short* __restrict__ wt2,
                                                 const float* __restrict__ dinv,
                                                 int N,
                                                 unsigned short* __restrict__ B16,
                                                 const unsigned short* __restrict__ C16h,
                                                 float* __restrict__ P0,
                                                 unsigned short* __restrict__ P1h) {
    __shared__ unsigned short lds[14336] __attribute__((aligned(16)));  // x:[0,8192) W:[8192,14336)
    int t = threadIdx.x;
    int v0 = blockIdx.x * 128;
    {
        const uint4* src = (const uint4*)wt2;
        uint4* dst = (uint4*)&lds[8192];
        for (int i = t; i < 768; i += 512) dst[i] = src[i];
    }
    {
        int row = t >> 2, s0 = (t & 3) * 2;
        int v = min(v0 + row, N - 1);
        const uint4* cp = (const uint4*)(C16h + (size_t)v * 64);
        uint4 u0 = cp[s0];
        uint4 u1 = cp[s0 + 1];
        int key = row & 7;
        *(uint4*)&lds[row * 64 + ((s0 ^ key) << 3)] = u0;
        *(uint4*)&lds[row * 64 + (((s0 + 1) ^ key) << 3)] = u1;
    }
    __syncthreads();

    int w = t >> 6, l = t & 63;
    int lr = l & 15, lk = l >> 4;
    int key = lr & 7;
    int arow = w * 16 + lr;
    f16x8 a0 = *(const f16x8*)&lds[arow * 64 + (((0 + lk) ^ key) << 3)];
    f16x8 a1 = *(const f16x8*)&lds[arow * 64 + (((4 + lk) ^ key) << 3)];
    f32x4 acc[6];
#pragma unroll
    for (int i = 0; i < 6; ++i) acc[i] = (f32x4){0.0f, 0.0f, 0.0f, 0.0f};
#pragma unroll
    for (int nt = 0; nt < 6; ++nt) {
        int bc = nt * 16 + lr;
        const unsigned short* wb = &lds[8192 + bc * 64];
        f16x8 b0 = *(const f16x8*)&wb[((0 + lk) ^ key) << 3];
        f16x8 b1v = *(const f16x8*)&wb[((4 + lk) ^ key) << 3];
        acc[nt] = __builtin_amdgcn_mfma_f32_16x16x32_f16(a0, b0, acc[nt], 0, 0, 0);
        acc[nt] = __builtin_amdgcn_mfma_f32_16x16x32_f16(a1, b1v, acc[nt], 0, 0, 0);
    }
    float4 dv4 = *(const float4*)&dinv[v0 + w * 16 + lk * 4];
    float dsc[4] = {dv4.x, dv4.y, dv4.z, dv4.w};
    // P0 f32 direct stores
#pragma unroll
    for (int nt = 0; nt < 2; ++nt) {
        int col = nt * 16 + lr;
#pragma unroll
        for (int r = 0; r < 4; ++r) {
            int v = v0 + w * 16 + lk * 4 + r;
            if (v < N) P0[(size_t)v * 32 + col] = acc[nt][r];
        }
    }
    __syncthreads();
    // repack P1 (cols 0..31) || D2-scaled (cols 32..63) as f16 [128][64]
#pragma unroll
    for (int nt = 2; nt < 4; ++nt) {
        int col = (nt - 2) * 16 + lr;
#pragma unroll
        for (int r = 0; r < 4; ++r) {
            int vloc = w * 16 + lk * 4 + r;
            lds[vloc * 64 + col] = f2h(acc[nt][r]);
        }
    }
#pragma unroll
    for (int nt = 4; nt < 6; ++nt) {
        int col = (nt - 2) * 16 + lr;
#pragma unroll
        for (int r = 0; r < 4; ++r) {
            int vloc = w * 16 + lk * 4 + r;
            lds[vloc * 64 + col] = f2h(acc[nt][r] * dsc[r]);
        }
    }
    __syncthreads();
#pragma unroll
    for (int q = 0; q < 2; ++q) {
        int i = q * 512 + t;          // 16B chunk id, 0..1023
        int row = i >> 3, ch = i & 7;
        int v = v0 + row;
        if (v < N) {
            uint4 val = ((const uint4*)lds)[i];
            unsigned short* dst = (ch < 4)
                ? (P1h + (size_t)v * 32 + ch * 8)
                : (B16 + (size_t)v * 32 + (ch - 4) * 8);
            *(uint4*)dst = val;
        }
    }
}

// Multi-node gather, packed f16: LPN lanes per node, NG = LPN/(PITCH/8)
// edge-groups. 4-deep unrolled (4 independent sdst+row loads in flight).
// Sources pre-scaled by dinv[c]; accumulate with v_pk_add_f16; single-stage
// packed xor-reduce; final convert to f32.
template <int PITCH, int LPN>
__device__ __forceinline__ void gatherH(const unsigned short* __restrict__ src,
                                        const int* __restrict__ sdst,
                                        int beg, int end, int grp, int fl,
                                        float a[8]) {
    constexpr int NG = LPN / (PITCH / 8);
    f16x8 acc;
#pragma unroll
    for (int q = 0; q < 8; ++q) acc[q] = (_Float16)0;
    int e = beg + grp;
    for (; e + 3 * NG < end; e += 4 * NG) {
        int c0 = sdst[e];
        int c1 = sdst[e + NG];
        int c2 = sdst[e + 2 * NG];
        int c3 = sdst[e + 3 * NG];
        f16x8 r0 = *(const f16x8*)(src + (size_t)c0 * PITCH + 8 * fl);
        f16x8 r1 = *(const f16x8*)(src + (size_t)c1 * PITCH + 8 * fl);
        f16x8 r2 = *(const f16x8*)(src + (size_t)c2 * PITCH + 8 * fl);
        f16x8 r3 = *(const f16x8*)(src + (size_t)c3 * PITCH + 8 * fl);
        acc = acc + r0;
        acc = acc + r1;
        acc = acc + r2;
        acc = acc + r3;
    }
    for (; e < end; e += NG) {
        int c = sdst[e];
        f16x8 r = *(const f16x8*)(src + (size_t)c * PITCH + 8 * fl);
        acc = acc + r;
    }
#pragma unroll
    for (int m = PITCH / 8; m < LPN; m <<= 1) {
        union { f16x8 h; int i4[4]; } u;
        u.h = acc;
#pragma unroll
        for (int q = 0; q < 4; ++q) u.i4[q] = __shfl_xor(u.i4[q], m);
        acc = acc + u.h;
    }
#pragma unroll
    for (int q = 0; q < 8; ++q) a[q] = (float)acc[q];
}

// Gather 1: B16[v] = f16( dinv[v] * (B16[v] - 2*dinv[v]*sum C16'[c]) )
// 16 lanes/node (4 nodes/wave), degree-sorted via perm.
__global__ void __launch_bounds__(BLK) k_gath1(const unsigned short* __restrict__ C16,
                                               unsigned short* __restrict__ B16,
                                               const float* __restrict__ dinv,
                                               const int* __restrict__ row_ptr,
                                               const int* __restrict__ sdst,
                                               const int* __restrict__ perm,
                                               int N) {
    int vidx = blockIdx.x * 16 + (threadIdx.x >> 4);
    if (vidx >= N) return;
    int v = perm[vidx];
    int ln = threadIdx.x & 15;
    int grp = ln >> 3, fl = ln & 7;
    float a[8];
    gatherH<64, 16>(C16, sdst, row_ptr[v], row_ptr[v + 1], grp, fl, a);
    if (grp == 0) {
        float di = dinv[v];
        float dv = -2.0f * di;
        unsigned short* p = B16 + (size_t)v * 64 + 8 * fl;
        f16x8 b = *(const f16x8*)p;
        uint4 o;
        o.x = pack2h(di * fmaf(dv, a[0], (float)b[0]), di * fmaf(dv, a[1], (float)b[1]));
        o.y = pack2h(di * fmaf(dv, a[2], (float)b[2]), di * fmaf(dv, a[3], (float)b[3]));
        o.z = pack2h(di * fmaf(dv, a[4], (float)b[4]), di * fmaf(dv, a[5], (float)b[5]));
        o.w = pack2h(di * fmaf(dv, a[6], (float)b[6]), di * fmaf(dv, a[7], (float)b[7]));
        *(uint4*)p = o;
    }
}

// Gather 2: C16h[v] (f16 H) = dropout(relu(D16[v] - dinv[v]*sum B16'[c])).
// 16 lanes/node, degree-sorted.
__global__ void __launch_bounds__(BLK) k_gath2(const unsigned short* __restrict__ D16,
                                               const unsigned short* __restrict__ B16,
                                               unsigned short* __restrict__ C16h,
                                               const unsigned long long* __restrict__ dmask,
                                               const float* __restrict__ dinv,
                                               const int* __restrict__ row_ptr,
                                               const int* __restrict__ sdst,
                                               const int* __restrict__ perm,
                                               int N) {
    int vidx = blockIdx.x * 16 + (threadIdx.x >> 4);
    if (vidx >= N) return;
    int v = perm[vidx];
    int ln = threadIdx.x & 15;
    int grp = ln >> 3, fl = ln & 7;
    float a[8];
    gatherH<64, 16>(B16, sdst, row_ptr[v], row_ptr[v + 1], grp, fl, a);
    if (grp == 0) {
        unsigned long long dm = dmask[v] >> (8 * fl);
        float dv = -dinv[v];
        f16x8 d = *(const f16x8*)(D16 + (size_t)v * 64 + 8 * fl);
        float o[8];
#pragma unroll
        for (int k = 0; k < 8; ++k)
            o[k] = fmaxf(fmaf(dv, a[k], (float)d[k]), 0.0f);
#pragma unroll
        for (int k = 0; k < 8; ++k)
            o[k] = ((dm >> k) & 1ull) ? 0.0f : o[k] * 2.0f;
        uint4 oo;
        oo.x = pack2h(o[0], o[1]); oo.y = pack2h(o[2], o[3]);
        oo.z = pack2h(o[4], o[5]); oo.w = pack2h(o[6], o[7]);
        *(uint4*)(C16h + (size_t)v * 64 + 8 * fl) = oo;
    }
}

// Gather 3: R16[v] = f16( dinv[v] * (P1[v] - 2*dinv[v]*sum D2'[c]) )
// 8 lanes/node (8 nodes/wave), degree-sorted.
__global__ void __launch_bounds__(BLK) k_gath3(const unsigned short* __restrict__ B16,
                                               const unsigned short* __restrict__ P1h,
                                               unsigned short* __restrict__ R16,
                                               const float* __restrict__ dinv,
                                               const int* __restrict__ row_ptr,
                                               const int* __restrict__ sdst,
                                               const int* __restrict__ perm,
                                               int N) {
    int vidx = blockIdx.x * 32 + (threadIdx.x >> 3);
    if (vidx >= N) return;
    int v = perm[vidx];
    int ln = threadIdx.x & 7;
    int grp = ln >> 2, fl = ln & 3;
    float a[8];
    gatherH<32, 8>(B16, sdst, row_ptr[v], row_ptr[v + 1], grp, fl, a);
    if (grp == 0) {
        float di = dinv[v];
        float dv = -2.0f * di;
        f16x8 d = *(const f16x8*)(P1h + (size_t)v * 32 + 8 * fl);
        uint4 o;
        o.x = pack2h(di * fmaf(dv, a[0], (float)d[0]), di * fmaf(dv, a[1], (float)d[1]));
        o.y = pack2h(di * fmaf(dv, a[2], (float)d[2]), di * fmaf(dv, a[3], (float)d[3]));
        o.z = pack2h(di * fmaf(dv, a[4], (float)d[4]), di * fmaf(dv, a[5], (float)d[5]));
        o.w = pack2h(di * fmaf(dv, a[6], (float)d[6]), di * fmaf(dv, a[7], (float)d[7]));
        *(uint4*)(R16 + (size_t)v * 32 + 8 * fl) = o;
    }
}

// Gather 4: out = log_softmax(P0 + b2 - dinv[v]*sum R16'[c]). 8 lanes/node,
// degree-sorted.
__global__ void __launch_bounds__(BLK) k_gath4(const unsigned short* __restrict__ R16,
                                               const float* __restrict__ P0,
                                               const float* __restrict__ dinv,
                                               const int* __restrict__ row_ptr,
                                               const int* __restrict__ sdst,
                                               const int* __restrict__ perm,
                                               const float* __restrict__ b2,
                                               int N, float* __restrict__ out) {
    int vidx = blockIdx.x * 32 + (threadIdx.x >> 3);
    if (vidx >= N) return;
    int v = perm[vidx];
    int ln = threadIdx.x & 7;
    int grp = ln >> 2, fl = ln & 3;
    float a[8];
    gatherH<32, 8>(R16, sdst, row_ptr[v], row_ptr[v + 1], grp, fl, a);
    float dv = -dinv[v];
    const float* dp = P0 + (size_t)v * 32 + 8 * fl;
    float4 dA = *(const float4*)dp;
    float4 dB = *(const float4*)(dp + 4);
    const float* bp = b2 + 8 * fl;
    float4 bA = *(const float4*)bp;
    float4 bB = *(const float4*)(bp + 4);
    float o[8];
    o[0] = fmaf(dv, a[0], dA.x + bA.x);
    o[1] = fmaf(dv, a[1], dA.y + bA.y);
    o[2] = fmaf(dv, a[2], dA.z + bA.z);
    o[3] = fmaf(dv, a[3], dA.w + bA.w);
    o[4] = fmaf(dv, a[4], dB.x + bB.x);
    o[5] = fmaf(dv, a[5], dB.y + bB.y);
    o[6] = fmaf(dv, a[6], dB.z + bB.z);
    o[7] = fmaf(dv, a[7], dB.w + bB.w);
    float m = o[0];
#pragma unroll
    for (int k = 1; k < 8; ++k) m = fmaxf(m, o[k]);
    m = fmaxf(m, __shfl_xor(m, 1));
    m = fmaxf(m, __shfl_xor(m, 2));
    float s = 0.0f;
#pragma unroll
    for (int k = 0; k < 8; ++k) s += __expf(o[k] - m);
    s += __shfl_xor(s, 1);
    s += __shfl_xor(s, 2);
    float lse = m + __logf(s);
    if (grp == 0) {
        float* op = out + (size_t)v * 32 + 8 * fl;
        *(float4*)op = make_float4(o[0] - lse, o[1] - lse, o[2] - lse, o[3] - lse);
        *(float4*)(op + 4) = make_float4(o[4] - lse, o[5] - lse, o[6] - lse, o[7] - lse);
    }
}

extern "C" void kernel_launch(void* const* d_in, const int* in_sizes, int n_in,
                              void* d_out, int out_size, void* d_ws, size_t ws_size,
                              hipStream_t stream) {
    const float* x  = (const float*)d_in[0];
    const int* ei   = (const int*)d_in[1];
    const float* W1 = (const float*)d_in[2];
    const float* b1 = (const float*)d_in[3];
    const float* W2 = (const float*)d_in[4];
    const float* b2 = (const float*)d_in[5];
    float* out = (float*)d_out;

    const int N = in_sizes[0] / 64;
    const int E = in_sizes[1] / 2;
    const int NB = (N + ROWB - 1) >> RB_SHIFT;

    char* ws = (char*)d_ws;
    size_t off = 0;
    auto alloc = [&](size_t bytes) -> void* {
        void* p = ws + off;
        off = (off + bytes + 511) & ~(size_t)511;
        return p;
    };
    int*      flags   = (int*)alloc(16);
    int*      deg     = (int*)alloc((size_t)N * 4);
    float*    dinv    = (float*)alloc((size_t)N * 4);
    int*      row_ptr = (int*)alloc(((size_t)N + 1) * 4);
    int*      blk_sum = (int*)alloc(4096);
    int*      bcnt    = (int*)alloc((size_t)NB * 4 + 512);  // + dhist[128]
    int*      dhist   = bcnt + NB;
    int*      perm    = (int*)alloc((size_t)N * 4);
    // Region shared over time: bdata (preproc) -> D16 (layer1 f16, N*64) ->
    // P0 (f32 N*32) || P1h (f16 N*32), written by dense3b after D16 is dead.
    size_t dbytes = (size_t)N * 64 * 4;
    size_t bdbytes = (size_t)NB * BCAP * 4;
    unsigned* bdata = (unsigned*)alloc(dbytes > bdbytes ? dbytes : bdbytes);
    unsigned short* D16 = (unsigned short*)bdata;
    float*    P0    = (float*)bdata;
    unsigned short* P1h = (unsigned short*)((char*)bdata + (size_t)N * 32 * 4);
    int*      sdst  = (int*)alloc((size_t)E * 4);
    unsigned short* C16h = (unsigned short*)alloc((size_t)N * 64 * 2);  // H (f16)
    unsigned short* B16 = (unsigned short*)alloc((size_t)N * 64 * 2);
    // C16 (layer-1 gather source, dead after gath1) shares with R16 (layer-2).
    unsigned short* C16 = (unsigned short*)alloc((size_t)N * 64 * 2);
    unsigned short* R16 = C16;
    unsigned long long* dmask = (unsigned long long*)alloc((size_t)N * 8);
    unsigned short* wt1 = (unsigned short*)alloc(12288 * 2);
    unsigned short* wt2 = (unsigned short*)alloc(6144 * 2);

    hipMemsetAsync(bcnt, 0, (size_t)NB * 4 + 512, stream);

    const int gW16 = (N + 15) / 16;
    const int gW32 = (N + 31) / 32;
    const int gDM = (N + 127) / 128;
    const int gN = (N + 255) / 256;
    const int nb = NB;
    const int gBin = (E + CHUNK - 1) / CHUNK;
    const int gDrop = (N * 64 + 255) / 256;

    k_init<<<gDrop + 1 + 72, 256, 0, stream>>>(N * 64, ei, W1, W2, flags, dmask,
                                               wt1, wt2, gDrop);
    k_bin<<<gBin, 256, 0, stream>>>(ei, E, flags, bcnt, bdata, NB);
    k_hist2<<<NB, 256, 0, stream>>>(bdata, bcnt, N, deg, dinv, blk_sum, dhist);
    k_scanB<<<1, 1024, 0, stream>>>(blk_sum, nb, dhist);
    k_perm<<<gN, 256, 0, stream>>>(deg, N, dhist, perm);
    k_place<<<NB, 256, 0, stream>>>(bdata, bcnt, deg, blk_sum, N, E, row_ptr, sdst);

    // Layer 1: B16=f16(x@W1[1]), C16=f16(dinv*(x@W1[2])), D16=f16(x@(W1[0]-W1[2])+b1);
    // B16 = dinv*(B16 - 2*dinv*S'(C16)); H = drop(relu(D16 - dinv*S'(B16)))
    k_dense3<<<gDM, 512, 0, stream>>>(x, wt1, b1, dinv, N, B16, C16, D16);
    k_gath1<<<gW16, BLK, 0, stream>>>(C16, B16, dinv, row_ptr, sdst, perm, N);
    k_gath2<<<gW16, BLK, 0, stream>>>(D16, B16, C16h, dmask, dinv, row_ptr, sdst, perm, N);

    // Layer 2: D0->P0 f32, D1->P1h f16 (pitch 32); D2 pre-scaled f16 in B16 (pitch 32);
    // R16 = dinv*(P1 - 2*dinv*S'(D2)); out = lsm(P0 + b2 - dinv*S'(R16))
    k_dense3b<<<gDM, 512, 0, stream>>>(wt2, dinv, N, B16, C16h, P0, P1h);
    k_gath3<<<gW32, BLK, 0, stream>>>(B16, P1h, R16, dinv, row_ptr, sdst, perm, N);
    k_gath4<<<gW32, BLK, 0, stream>>>(R16, P0, dinv, row_ptr, sdst, perm, b2, N, out);
}

// Round 8
// 272.569 us; speedup vs baseline: 3.2118x; 1.0848x over previous
//
#include <hip/hip_runtime.h>

// ChebNet K=3, W-first form: ChebConv(H) = H@(W0-W2) + S·(H@W1 + 2·S·(H@W2)).
// Round 20: (1) REVERT degree-permutation (round 19: +21us -- perm destroyed
// sequential locality of row_ptr/sdst/epilogue rows); (2) gathers go NG=1:
// lanes-per-node = PITCH/8 (8 lanes pitch-64, 4 lanes pitch-32) -> zero
// shuffle-reduce, 100% epilogue lane use, 2x nodes/wave (8 resp. 16);
// 4-deep unrolled loads keep latency covered. Launch fusions kept (11 total).

static constexpr int BLK = 256;
static constexpr int ROWB = 256;
static constexpr int RB_SHIFT = 8;
static constexpr int BCAP = 6144;
static constexpr int CHUNK = 8192;

typedef _Float16 f16x8 __attribute__((ext_vector_type(8)));
typedef _Float16 f16x2 __attribute__((ext_vector_type(2)));
typedef float f32x4 __attribute__((ext_vector_type(4)));

__device__ __forceinline__ unsigned rotl32(unsigned x, int r) {
    return (x << r) | (x >> (32 - r));
}

// JAX partitionable threefry word for element i:
// (b1,b2) = threefry2x32(key=(0,42), counter=(0,i)); word = b1 ^ b2.
__device__ __forceinline__ unsigned tf_word(unsigned i) {
    const unsigned ks0 = 0u;
    const unsigned ks1 = 42u;
    const unsigned ks2 = 0u ^ 42u ^ 0x1BD11BDAu;
    unsigned x0 = 0u + ks0;
    unsigned x1 = i + ks1;
#define TF_RND(r) { x0 += x1; x1 = rotl32(x1, (r)); x1 ^= x0; }
    TF_RND(13) TF_RND(15) TF_RND(26) TF_RND(6)
    x0 += ks1; x1 += ks2 + 1u;
    TF_RND(17) TF_RND(29) TF_RND(16) TF_RND(24)
    x0 += ks2; x1 += ks0 + 2u;
    TF_RND(13) TF_RND(15) TF_RND(26) TF_RND(6)
    x0 += ks0; x1 += ks1 + 3u;
    TF_RND(17) TF_RND(29) TF_RND(16) TF_RND(24)
    x0 += ks1; x1 += ks2 + 4u;
    TF_RND(13) TF_RND(15) TF_RND(26) TF_RND(6)
    x0 += ks2; x1 += ks0 + 5u;
#undef TF_RND
    return x0 ^ x1;
}

// f16 pack/unpack
__device__ __forceinline__ unsigned short f2h(float f) {
    union { _Float16 h; unsigned short u; } c; c.h = (_Float16)f; return c.u;
}
__device__ __forceinline__ unsigned pack2h(float a, float b) {
    union { f16x2 h; unsigned u; } c;
    c.h[0] = (_Float16)a; c.h[1] = (_Float16)b;
    return c.u;
}

// Fused init: blocks [0,gDrop) dropout mask; block gDrop int64-detect;
// blocks (gDrop, gDrop+72] weight prep (fp16, transposed, pre-XOR-swizzled).
__global__ void __launch_bounds__(256) k_init(int NW, const int* __restrict__ ei,
                                              const float* __restrict__ W1,
                                              const float* __restrict__ W2,
                                              int* __restrict__ flags,
                                              unsigned long long* __restrict__ dmask,
                                              unsigned short* __restrict__ wt1,
                                              unsigned short* __restrict__ wt2,
                                              int gDrop) {
    int b = blockIdx.x;
    int t = threadIdx.x;
    if (b < gDrop) {
        int idx = b * 256 + t;
        unsigned word = (idx < NW) ? tf_word((unsigned)idx) : 0u;
        unsigned long long bal = __ballot(word >> 31);
        if ((t & 63) == 0 && idx < NW) dmask[idx >> 6] = bal;
        return;
    }
    if (b == gDrop) {
        __shared__ int cnt_nz;
        if (t == 0) cnt_nz = 0;
        __syncthreads();
        if (ei[2 * t + 1] != 0) atomicAdd(&cnt_nz, 1);
        __syncthreads();
        if (t == 0) flags[0] = (cnt_nz == 0) ? 1 : 0;
        return;
    }
    int idx = (b - gDrop - 1) * 256 + t;
    if (idx < 12288) {
        int c = idx >> 6, r6 = idx & 63;
        int slot = (r6 >> 3) ^ (c & 7);
        int k = slot * 8 + (r6 & 7);
        float v;
        if (c < 64)       v = W1[k * 64 + c] - W1[8192 + k * 64 + c];
        else if (c < 128) v = W1[4096 + k * 64 + (c - 64)];
        else              v = W1[8192 + k * 64 + (c - 128)];
        wt1[idx] = f2h(v);
    } else {
        int j = idx - 12288;
        int c = j >> 6, r6 = j & 63;
        int slot = (r6 >> 3) ^ (c & 7);
        int k = slot * 8 + (r6 & 7);
        float v;
        if (c < 32)      v = W2[k * 32 + c] - W2[4096 + k * 32 + c];
        else if (c < 64) v = W2[2048 + k * 32 + (c - 32)];
        else             v = W2[4096 + k * 32 + (c - 64)];
        wt2[j] = f2h(v);
    }
}

// Pass 1: bin edges into row-buckets, LDS-staged for coalesced writes.
__global__ void __launch_bounds__(256) k_bin(const int* __restrict__ ei, int E,
                                             const int* __restrict__ flags,
                                             int* __restrict__ bcnt,
                                             unsigned* __restrict__ bdata, int NB) {
    __shared__ unsigned sval[CHUNK];
    __shared__ unsigned short sbkt[CHUNK];
    __shared__ int h[512], ex[512], cur[512], basep[512];
    int t = threadIdx.x;
    int start = blockIdx.x * CHUNK;
    int lim = min(CHUNK, E - start);
    bool i64 = flags[0] != 0;
    h[t] = 0; h[t + 256] = 0;
    __syncthreads();
    unsigned vv[32];
    unsigned short bb_[32];
#pragma unroll
    for (int k = 0; k < 32; ++k) {
        int idx = k * 256 + t;
        int e = start + idx;
        if (idx < lim) {
            int r, c;
            if (i64) { r = ei[2 * e]; c = ei[2 * (E + e)]; }
            else     { r = ei[e];     c = ei[E + e]; }
            int b = r >> RB_SHIFT;
            vv[k] = ((unsigned)(r & (ROWB - 1)) << 17) | (unsigned)c;
            bb_[k] = (unsigned short)b;
            atomicAdd(&h[b], 1);
        } else {
            bb_[k] = 0xFFFF;
        }
    }
    __syncthreads();
    int i0 = t, i1 = t + 256;
    ex[i0] = h[i0]; ex[i1] = h[i1];
    __syncthreads();
    for (int off = 1; off < 512; off <<= 1) {
        int v0 = (i0 >= off) ? ex[i0 - off] : 0;
        int v1 = (i1 >= off) ? ex[i1 - off] : 0;
        __syncthreads();
        ex[i0] += v0; ex[i1] += v1;
        __syncthreads();
    }
    int e0 = ex[i0] - h[i0], e1 = ex[i1] - h[i1];
    __syncthreads();
    ex[i0] = e0; cur[i0] = e0;
    ex[i1] = e1; cur[i1] = e1;
    if (i0 < NB && h[i0] > 0) basep[i0] = atomicAdd(&bcnt[i0], h[i0]);
    if (i1 < NB && h[i1] > 0) basep[i1] = atomicAdd(&bcnt[i1], h[i1]);
    __syncthreads();
#pragma unroll
    for (int k = 0; k < 32; ++k) {
        if (bb_[k] != 0xFFFF) {
            int p = atomicAdd(&cur[bb_[k]], 1);
            sval[p] = vv[k];
            sbkt[p] = bb_[k];
        }
    }
    __syncthreads();
    for (int i = t; i < lim; i += 256) {
        int b = sbkt[i];
        int gpos = basep[b] + (i - ex[b]);
        if (gpos < BCAP) bdata[(size_t)b * BCAP + gpos] = sval[i];
    }
}

// hist + dinv + block-sum, fused.
__global__ void __launch_bounds__(256) k_hist2(const unsigned* __restrict__ bdata,
                                               const int* __restrict__ bcnt,
                                               int N, int* __restrict__ deg,
                                               float* __restrict__ dinv,
                                               int* __restrict__ blk_sum) {
    __shared__ int h[ROWB];
    int t = threadIdx.x, b = blockIdx.x;
    h[t] = 0;
    __syncthreads();
    int cnt = min(bcnt[b], BCAP);
    for (int i = t; i < cnt; i += 256)
        atomicAdd(&h[bdata[(size_t)b * BCAP + i] >> 17], 1);
    __syncthreads();
    int r = b * ROWB + t;
    int d = h[t];
    if (r < N) {
        deg[r] = d;
        dinv[r] = (d > 0) ? rsqrtf((float)d) : 0.0f;
    }
    __syncthreads();
    for (int off = 128; off > 0; off >>= 1) {
        if (t < off) h[t] += h[t + off];
        __syncthreads();
    }
    if (t == 0) blk_sum[b] = h[0];
}

// Scan blk_sum (exclusive), one block.
__global__ void k_scanB(int* __restrict__ blk_sum, int nb) {
    __shared__ int lds[1024];
    int t = threadIdx.x;
    int v = (t < nb) ? blk_sum[t] : 0;
    lds[t] = v;
    __syncthreads();
    for (int off = 1; off < 1024; off <<= 1) {
        int val = (t >= off) ? lds[t - off] : 0;
        __syncthreads();
        lds[t] += val;
        __syncthreads();
    }
    if (t < nb) blk_sum[t] = lds[t] - v;
}

// place + scanC fused: local exclusive scan of deg recomputes row_ptr.
__global__ void __launch_bounds__(256) k_place(const unsigned* __restrict__ bdata,
                                               const int* __restrict__ bcnt,
                                               const int* __restrict__ deg,
                                               const int* __restrict__ blk_sum,
                                               int N, int E,
                                               int* __restrict__ row_ptr,
                                               int* __restrict__ sdst) {
    __shared__ int cur[ROWB];
    __shared__ int sc[ROWB];
    __shared__ int staged[BCAP];
    int t = threadIdx.x, b = blockIdx.x;
    int r = b * ROWB + t;
    int d = (r < N) ? deg[r] : 0;
    sc[t] = d;
    __syncthreads();
    for (int off = 1; off < ROWB; off <<= 1) {
        int val = (t >= off) ? sc[t - off] : 0;
        __syncthreads();
        sc[t] += val;
        __syncthreads();
    }
    int excl = sc[t] - d;
    int rbase = blk_sum[b];
    if (r < N) row_ptr[r] = rbase + excl;
    if (b == gridDim.x - 1 && t == ROWB - 1) row_ptr[N] = E;
    cur[t] = excl;
    __syncthreads();
    int cnt = min(bcnt[b], BCAP);
    for (int i = t; i < cnt; i += 256) {
        unsigned val = bdata[(size_t)b * BCAP + i];
        int p = atomicAdd(&cur[val >> 17], 1);
        staged[p] = (int)(val & 0x1FFFFu);
    }
    __syncthreads();
    for (int i = t; i < cnt; i += 256) sdst[rbase + i] = staged[i];
}

// MFMA dense, layer 1. 128 nodes/block, 512 threads = 8 waves, each wave owns
// one 16-row M-tile x 12 N-tiles (192 cols = D | B | C), K=64 in 2 steps of
// v_mfma_f32_16x16x32_f16. All outputs f16: D16 (=x@(W0-W2)+b1, pitch 64),
// B16 (=x@W1, unscaled), C16 (=dinv*(x@W2)).
__global__ void __launch_bounds__(512) k_dense3(const float* __restrict__ x,
                                                const unsigned short* __restrict__ wt1,
                                                const float* __restrict__ b1,
                                                const float* __restrict__ dinv,
                                                int N,
                                                unsigned short* __restrict__ B16,
                                                unsigned short* __restrict__ C16,
                                                unsigned short* __restrict__ D16) {
    __shared__ unsigned short lds[20480] __attribute__((aligned(16)));  // x:[0,8192) W:[8192,20480)
    __shared__ float sb[64];
    int t = threadIdx.x;
    int v0 = blockIdx.x * 128;
    {
        const uint4* src = (const uint4*)wt1;
        uint4* dst = (uint4*)&lds[8192];
        for (int i = t; i < 1536; i += 512) dst[i] = src[i];
    }
    if (t < 64) sb[t] = b1[t];
    {
        int row = t >> 2, c0 = (t & 3) << 4;
        int v = min(v0 + row, N - 1);
        const float* xp = x + (size_t)v * 64 + c0;
        float4 f0 = *(const float4*)xp;
        float4 f1 = *(const float4*)(xp + 4);
        float4 f2 = *(const float4*)(xp + 8);
        float4 f3 = *(const float4*)(xp + 12);
        int key = row & 7;
        int s0 = c0 >> 3;
        f16x8 h0, h1;
        h0[0] = (_Float16)f0.x; h0[1] = (_Float16)f0.y;
        h0[2] = (_Float16)f0.z; h0[3] = (_Float16)f0.w;
        h0[4] = (_Float16)f1.x; h0[5] = (_Float16)f1.y;
        h0[6] = (_Float16)f1.z; h0[7] = (_Float16)f1.w;
        h1[0] = (_Float16)f2.x; h1[1] = (_Float16)f2.y;
        h1[2] = (_Float16)f2.z; h1[3] = (_Float16)f2.w;
        h1[4] = (_Float16)f3.x; h1[5] = (_Float16)f3.y;
        h1[6] = (_Float16)f3.z; h1[7] = (_Float16)f3.w;
        *(f16x8*)&lds[row * 64 + ((s0 ^ key) << 3)] = h0;
        *(f16x8*)&lds[row * 64 + (((s0 + 1) ^ key) << 3)] = h1;
    }
    __syncthreads();

    int w = t >> 6, l = t & 63;
    int lr = l & 15, lk = l >> 4;
    int key = lr & 7;
    int arow = w * 16 + lr;
    f16x8 a0 = *(const f16x8*)&lds[arow * 64 + (((0 + lk) ^ key) << 3)];
    f16x8 a1 = *(const f16x8*)&lds[arow * 64 + (((4 + lk) ^ key) << 3)];
    f32x4 acc[12];
#pragma unroll
    for (int i = 0; i < 12; ++i) acc[i] = (f32x4){0.0f, 0.0f, 0.0f, 0.0f};
#pragma unroll
    for (int nt = 0; nt < 12; ++nt) {
        int bc = nt * 16 + lr;
        const unsigned short* wb = &lds[8192 + bc * 64];
        f16x8 b0 = *(const f16x8*)&wb[((0 + lk) ^ key) << 3];
        f16x8 b1v = *(const f16x8*)&wb[((4 + lk) ^ key) << 3];
        acc[nt] = __builtin_amdgcn_mfma_f32_16x16x32_f16(a0, b0, acc[nt], 0, 0, 0);
        acc[nt] = __builtin_amdgcn_mfma_f32_16x16x32_f16(a1, b1v, acc[nt], 0, 0, 0);
    }
    float4 dv4 = *(const float4*)&dinv[v0 + w * 16 + lk * 4];
    float dsc[4] = {dv4.x, dv4.y, dv4.z, dv4.w};
    __syncthreads();
    // Phase 1: D = acc[0..3]+b1 -> f16 [128][64] in lds
#pragma unroll
    for (int nt = 0; nt < 4; ++nt) {
        int col = nt * 16 + lr;
        float bv = sb[col];
#pragma unroll
        for (int r = 0; r < 4; ++r) {
            int vloc = w * 16 + lk * 4 + r;
            lds[vloc * 64 + col] = f2h(acc[nt][r] + bv);
        }
    }
    __syncthreads();
#pragma unroll
    for (int q = 0; q < 2; ++q) {
        int i = q * 512 + t;          // 16B chunk id, 0..1023
        int row = i >> 3, ch = i & 7;
        int v = v0 + row;
        if (v < N) *(uint4*)(D16 + (size_t)v * 64 + ch * 8) = ((const uint4*)lds)[i];
    }
    __syncthreads();
    // Phase 2: B16 (unscaled) || C16 (dinv-scaled) -> f16 [128][128] in lds
#pragma unroll
    for (int nt = 4; nt < 8; ++nt) {
        int col = (nt - 4) * 16 + lr;
#pragma unroll
        for (int r = 0; r < 4; ++r) {
            int vloc = w * 16 + lk * 4 + r;
            lds[vloc * 128 + col] = f2h(acc[nt][r]);
        }
    }
#pragma unroll
    for (int nt = 8; nt < 12; ++nt) {
        int col = (nt - 4) * 16 + lr;
#pragma unroll
        for (int r = 0; r < 4; ++r) {
            int vloc = w * 16 + lk * 4 + r;
            lds[vloc * 128 + col] = f2h(acc[nt][r] * dsc[r]);
        }
    }
    __syncthreads();
#pragma unroll
    for (int q = 0; q < 4; ++q) {
        int i = q * 512 + t;          // 16B chunk id, 0..2047
        int row = i >> 4, ch = i & 15;
        int v = v0 + row;
        if (v < N) {
            uint4 val = *(const uint4*)&lds[i * 8];
            unsigned short* dst = (ch < 8)
                ? (B16 + (size_t)v * 64 + ch * 8)
                : (C16 + (size_t)v * 64 + (ch - 8) * 8);
            *(uint4*)dst = val;
        }
    }
}

// MFMA dense, layer 2. 128 nodes/block, 512 threads. H read as f16 (C16h).
// nt0,1 -> P0 f32 pitch 32 (D0=H@(W2[0]-W2[2]), direct stores);
// nt2,3 -> P1 f16 pitch 32 (D1=H@W2[1]); nt4,5 -> D2=dinv*(H@W2[2]) f16 pitch 32.
__global__ void __launch_bounds__(512) k_dense3b(const unsigned short* __restrict__ wt2,
                                                 const float* __restrict__ dinv,
                                                 int N,
                                                 unsigned short* __restrict__ B16,
                                                 const unsigned short* __restrict__ C16h,
                                                 float* __restrict__ P0,
                                                 unsigned short* __restrict__ P1h) {
    __shared__ unsigned short lds[14336] __attribute__((aligned(16)));  // x:[0,8192) W:[8192,14336)
    int t = threadIdx.x;
    int v0 = blockIdx.x * 128;
    {
        const uint4* src = (const uint4*)wt2;
        uint4* dst = (uint4*)&lds[8192];
        for (int i = t; i < 768; i += 512) dst[i] = src[i];
    }
    {
        int row = t >> 2, s0 = (t & 3) * 2;
        int v = min(v0 + row, N - 1);
        const uint4* cp = (const uint4*)(C16h + (size_t)v * 64);
        uint4 u0 = cp[s0];
        uint4 u1 = cp[s0 + 1];
        int key = row & 7;
        *(uint4*)&lds[row * 64 + ((s0 ^ key) << 3)] = u0;
        *(uint4*)&lds[row * 64 + (((s0 + 1) ^ key) << 3)] = u1;
    }
    __syncthreads();

    int w = t >> 6, l = t & 63;
    int lr = l & 15, lk = l >> 4;
    int key = lr & 7;
    int arow = w * 16 + lr;
    f16x8 a0 = *(const f16x8*)&lds[arow * 64 + (((0 + lk) ^ key) << 3)];
    f16x8 a1 = *(const f16x8*)&lds[arow * 64 + (((4 + lk) ^ key) << 3)];
    f32x4 acc[6];
#pragma unroll
    for (int i = 0; i < 6; ++i) acc[i] = (f32x4){0.0f, 0.0f, 0.0f, 0.0f};
#pragma unroll
    for (int nt = 0; nt < 6; ++nt) {
        int bc = nt * 16 + lr;
        const unsigned short* wb = &lds[8192 + bc * 64];
        f16x8 b0 = *(const f16x8*)&wb[((0 + lk) ^ key) << 3];
        f16x8 b1v = *(const f16x8*)&wb[((4 + lk) ^ key) << 3];
        acc[nt] = __builtin_amdgcn_mfma_f32_16x16x32_f16(a0, b0, acc[nt], 0, 0, 0);
        acc[nt] = __builtin_amdgcn_mfma_f32_16x16x32_f16(a1, b1v, acc[nt], 0, 0, 0);
    }
    float4 dv4 = *(const float4*)&dinv[v0 + w * 16 + lk * 4];
    float dsc[4] = {dv4.x, dv4.y, dv4.z, dv4.w};
    // P0 f32 direct stores
#pragma unroll
    for (int nt = 0; nt < 2; ++nt) {
        int col = nt * 16 + lr;
#pragma unroll
        for (int r = 0; r < 4; ++r) {
            int v = v0 + w * 16 + lk * 4 + r;
            if (v < N) P0[(size_t)v * 32 + col] = acc[nt][r];
        }
    }
    __syncthreads();
    // repack P1 (cols 0..31) || D2-scaled (cols 32..63) as f16 [128][64]
#pragma unroll
    for (int nt = 2; nt < 4; ++nt) {
        int col = (nt - 2) * 16 + lr;
#pragma unroll
        for (int r = 0; r < 4; ++r) {
            int vloc = w * 16 + lk * 4 + r;
            lds[vloc * 64 + col] = f2h(acc[nt][r]);
        }
    }
#pragma unroll
    for (int nt = 4; nt < 6; ++nt) {
        int col = (nt - 2) * 16 + lr;
#pragma unroll
        for (int r = 0; r < 4; ++r) {
            int vloc = w * 16 + lk * 4 + r;
            lds[vloc * 64 + col] = f2h(acc[nt][r] * dsc[r]);
        }
    }
    __syncthreads();
#pragma unroll
    for (int q = 0; q < 2; ++q) {
        int i = q * 512 + t;          // 16B chunk id, 0..1023
        int row = i >> 3, ch = i & 7;
        int v = v0 + row;
        if (v < N) {
            uint4 val = ((const uint4*)lds)[i];
            unsigned short* dst = (ch < 4)
                ? (P1h + (size_t)v * 32 + ch * 8)
                : (B16 + (size_t)v * 32 + (ch - 4) * 8);
            *(uint4*)dst = val;
        }
    }
}

// NG=1 gather, packed f16: PITCH/8 lanes per node, each lane owns one 16-B
// feature slice; no cross-lane reduce. 4-deep unrolled (4 independent
// sdst+row loads in flight). Sources pre-scaled by dinv[c].
template <int PITCH>
__device__ __forceinline__ void gatherH(const unsigned short* __restrict__ src,
                                        const int* __restrict__ sdst,
                                        int beg, int end, int fl,
                                        float a[8]) {
    f16x8 acc;
#pragma unroll
    for (int q = 0; q < 8; ++q) acc[q] = (_Float16)0;
    int e = beg;
    for (; e + 3 < end; e += 4) {
        int c0 = sdst[e];
        int c1 = sdst[e + 1];
        int c2 = sdst[e + 2];
        int c3 = sdst[e + 3];
        f16x8 r0 = *(const f16x8*)(src + (size_t)c0 * PITCH + 8 * fl);
        f16x8 r1 = *(const f16x8*)(src + (size_t)c1 * PITCH + 8 * fl);
        f16x8 r2 = *(const f16x8*)(src + (size_t)c2 * PITCH + 8 * fl);
        f16x8 r3 = *(const f16x8*)(src + (size_t)c3 * PITCH + 8 * fl);
        acc = acc + r0;
        acc = acc + r1;
        acc = acc + r2;
        acc = acc + r3;
    }
    for (; e < end; ++e) {
        int c = sdst[e];
        f16x8 r = *(const f16x8*)(src + (size_t)c * PITCH + 8 * fl);
        acc = acc + r;
    }
#pragma unroll
    for (int q = 0; q < 8; ++q) a[q] = (float)acc[q];
}

// Gather 1: B16[v] = f16( dinv[v] * (B16[v] - 2*dinv[v]*sum C16'[c]) )
// 8 lanes/node (8 nodes/wave, 32 nodes/block).
__global__ void __launch_bounds__(BLK) k_gath1(const unsigned short* __restrict__ C16,
                                               unsigned short* __restrict__ B16,
                                               const float* __restrict__ dinv,
                                               const int* __restrict__ row_ptr,
                                               const int* __restrict__ sdst,
                                               int N) {
    int v = blockIdx.x * 32 + (threadIdx.x >> 3);
    if (v >= N) return;
    int fl = threadIdx.x & 7;
    float a[8];
    gatherH<64>(C16, sdst, row_ptr[v], row_ptr[v + 1], fl, a);
    float di = dinv[v];
    float dv = -2.0f * di;
    unsigned short* p = B16 + (size_t)v * 64 + 8 * fl;
    f16x8 b = *(const f16x8*)p;
    uint4 o;
    o.x = pack2h(di * fmaf(dv, a[0], (float)b[0]), di * fmaf(dv, a[1], (float)b[1]));
    o.y = pack2h(di * fmaf(dv, a[2], (float)b[2]), di * fmaf(dv, a[3], (float)b[3]));
    o.z = pack2h(di * fmaf(dv, a[4], (float)b[4]), di * fmaf(dv, a[5], (float)b[5]));
    o.w = pack2h(di * fmaf(dv, a[6], (float)b[6]), di * fmaf(dv, a[7], (float)b[7]));
    *(uint4*)p = o;
}

// Gather 2: C16h[v] (f16 H) = dropout(relu(D16[v] - dinv[v]*sum B16'[c])).
// 8 lanes/node.
__global__ void __launch_bounds__(BLK) k_gath2(const unsigned short* __restrict__ D16,
                                               const unsigned short* __restrict__ B16,
                                               unsigned short* __restrict__ C16h,
                                               const unsigned long long* __restrict__ dmask,
                                               const float* __restrict__ dinv,
                                               const int* __restrict__ row_ptr,
                                               const int* __restrict__ sdst,
                                               int N) {
    int v = blockIdx.x * 32 + (threadIdx.x >> 3);
    if (v >= N) return;
    int fl = threadIdx.x & 7;
    float a[8];
    gatherH<64>(B16, sdst, row_ptr[v], row_ptr[v + 1], fl, a);
    unsigned long long dm = dmask[v] >> (8 * fl);
    float dv = -dinv[v];
    f16x8 d = *(const f16x8*)(D16 + (size_t)v * 64 + 8 * fl);
    float o[8];
#pragma unroll
    for (int k = 0; k < 8; ++k)
        o[k] = fmaxf(fmaf(dv, a[k], (float)d[k]), 0.0f);
#pragma unroll
    for (int k = 0; k < 8; ++k)
        o[k] = ((dm >> k) & 1ull) ? 0.0f : o[k] * 2.0f;
    uint4 oo;
    oo.x = pack2h(o[0], o[1]); oo.y = pack2h(o[2], o[3]);
    oo.z = pack2h(o[4], o[5]); oo.w = pack2h(o[6], o[7]);
    *(uint4*)(C16h + (size_t)v * 64 + 8 * fl) = oo;
}

// Gather 3: R16[v] = f16( dinv[v] * (P1[v] - 2*dinv[v]*sum D2'[c]) )
// 4 lanes/node (16 nodes/wave, 64 nodes/block).
__global__ void __launch_bounds__(BLK) k_gath3(const unsigned short* __restrict__ B16,
                                               const unsigned short* __restrict__ P1h,
                                               unsigned short* __restrict__ R16,
                                               const float* __restrict__ dinv,
                                               const int* __restrict__ row_ptr,
                                               const int* __restrict__ sdst,
                                               int N) {
    int v = blockIdx.x * 64 + (threadIdx.x >> 2);
    if (v >= N) return;
    int fl = threadIdx.x & 3;
    float a[8];
    gatherH<32>(B16, sdst, row_ptr[v], row_ptr[v + 1], fl, a);
    float di = dinv[v];
    float dv = -2.0f * di;
    f16x8 d = *(const f16x8*)(P1h + (size_t)v * 32 + 8 * fl);
    uint4 o;
    o.x = pack2h(di * fmaf(dv, a[0], (float)d[0]), di * fmaf(dv, a[1], (float)d[1]));
    o.y = pack2h(di * fmaf(dv, a[2], (float)d[2]), di * fmaf(dv, a[3], (float)d[3]));
    o.z = pack2h(di * fmaf(dv, a[4], (float)d[4]), di * fmaf(dv, a[5], (float)d[5]));
    o.w = pack2h(di * fmaf(dv, a[6], (float)d[6]), di * fmaf(dv, a[7], (float)d[7]));
    *(uint4*)(R16 + (size_t)v * 32 + 8 * fl) = o;
}

// Gather 4: out = log_softmax(P0 + b2 - dinv[v]*sum R16'[c]). 4 lanes/node;
// softmax reduce via xor 1,2 within the node's 4 lanes.
__global__ void __launch_bounds__(BLK) k_gath4(const unsigned short* __restrict__ R16,
                                               const float* __restrict__ P0,
                                               const float* __restrict__ dinv,
                                               const int* __restrict__ row_ptr,
                                               const int* __restrict__ sdst,
                                               const float* __restrict__ b2,
                                               int N, float* __restrict__ out) {
    int v = blockIdx.x * 64 + (threadIdx.x >> 2);
    if (v >= N) return;
    int fl = threadIdx.x & 3;
    float a[8];
    gatherH<32>(R16, sdst, row_ptr[v], row_ptr[v + 1], fl, a);
    float dv = -dinv[v];
    const float* dp = P0 + (size_t)v * 32 + 8 * fl;
    float4 dA = *(const float4*)dp;
    float4 dB = *(const float4*)(dp + 4);
    const float* bp = b2 + 8 * fl;
    float4 bA = *(const float4*)bp;
    float4 bB = *(const float4*)(bp + 4);
    float o[8];
    o[0] = fmaf(dv, a[0], dA.x + bA.x);
    o[1] = fmaf(dv, a[1], dA.y + bA.y);
    o[2] = fmaf(dv, a[2], dA.z + bA.z);
    o[3] = fmaf(dv, a[3], dA.w + bA.w);
    o[4] = fmaf(dv, a[4], dB.x + bB.x);
    o[5] = fmaf(dv, a[5], dB.y + bB.y);
    o[6] = fmaf(dv, a[6], dB.z + bB.z);
    o[7] = fmaf(dv, a[7], dB.w + bB.w);
    float m = o[0];
#pragma unroll
    for (int k = 1; k < 8; ++k) m = fmaxf(m, o[k]);
    m = fmaxf(m, __shfl_xor(m, 1));
    m = fmaxf(m, __shfl_xor(m, 2));
    float s = 0.0f;
#pragma unroll
    for (int k = 0; k < 8; ++k) s += __expf(o[k] - m);
    s += __shfl_xor(s, 1);
    s += __shfl_xor(s, 2);
    float lse = m + __logf(s);
    float* op = out + (size_t)v * 32 + 8 * fl;
    *(float4*)op = make_float4(o[0] - lse, o[1] - lse, o[2] - lse, o[3] - lse);
    *(float4*)(op + 4) = make_float4(o[4] - lse, o[5] - lse, o[6] - lse, o[7] - lse);
}

extern "C" void kernel_launch(void* const* d_in, const int* in_sizes, int n_in,
                              void* d_out, int out_size, void* d_ws, size_t ws_size,
                              hipStream_t stream) {
    const float* x  = (const float*)d_in[0];
    const int* ei   = (const int*)d_in[1];
    const float* W1 = (const float*)d_in[2];
    const float* b1 = (const float*)d_in[3];
    const float* W2 = (const float*)d_in[4];
    const float* b2 = (const float*)d_in[5];
    float* out = (float*)d_out;

    const int N = in_sizes[0] / 64;
    const int E = in_sizes[1] / 2;
    const int NB = (N + ROWB - 1) >> RB_SHIFT;

    char* ws = (char*)d_ws;
    size_t off = 0;
    auto alloc = [&](size_t bytes) -> void* {
        void* p = ws + off;
        off = (off + bytes + 511) & ~(size_t)511;
        return p;
    };
    int*      flags   = (int*)alloc(16);
    int*      deg     = (int*)alloc((size_t)N * 4);
    float*    dinv    = (float*)alloc((size_t)N * 4);
    int*      row_ptr = (int*)alloc(((size_t)N + 1) * 4);
    int*      blk_sum = (int*)alloc(4096);
    int*      bcnt    = (int*)alloc((size_t)NB * 4);
    // Region shared over time: bdata (preproc) -> D16 (layer1 f16, N*64) ->
    // P0 (f32 N*32) || P1h (f16 N*32), written by dense3b after D16 is dead.
    size_t dbytes = (size_t)N * 64 * 4;
    size_t bdbytes = (size_t)NB * BCAP * 4;
    unsigned* bdata = (unsigned*)alloc(dbytes > bdbytes ? dbytes : bdbytes);
    unsigned short* D16 = (unsigned short*)bdata;
    float*    P0    = (float*)bdata;
    unsigned short* P1h = (unsigned short*)((char*)bdata + (size_t)N * 32 * 4);
    int*      sdst  = (int*)alloc((size_t)E * 4);
    unsigned short* C16h = (unsigned short*)alloc((size_t)N * 64 * 2);  // H (f16)
    unsigned short* B16 = (unsigned short*)alloc((size_t)N * 64 * 2);
    // C16 (layer-1 gather source, dead after gath1) shares with R16 (layer-2).
    unsigned short* C16 = (unsigned short*)alloc((size_t)N * 64 * 2);
    unsigned short* R16 = C16;
    unsigned long long* dmask = (unsigned long long*)alloc((size_t)N * 8);
    unsigned short* wt1 = (unsigned short*)alloc(12288 * 2);
    unsigned short* wt2 = (unsigned short*)alloc(6144 * 2);

    hipMemsetAsync(bcnt, 0, (size_t)NB * 4, stream);

    const int gW32 = (N + 31) / 32;
    const int gW64 = (N + 63) / 64;
    const int gDM = (N + 127) / 128;
    const int nb = NB;
    const int gBin = (E + CHUNK - 1) / CHUNK;
    const int gDrop = (N * 64 + 255) / 256;

    k_init<<<gDrop + 1 + 72, 256, 0, stream>>>(N * 64, ei, W1, W2, flags, dmask,
                                               wt1, wt2, gDrop);
    k_bin<<<gBin, 256, 0, stream>>>(ei, E, flags, bcnt, bdata, NB);
    k_hist2<<<NB, 256, 0, stream>>>(bdata, bcnt, N, deg, dinv, blk_sum);
    k_scanB<<<1, 1024, 0, stream>>>(blk_sum, nb);
    k_place<<<NB, 256, 0, stream>>>(bdata, bcnt, deg, blk_sum, N, E, row_ptr, sdst);

    // Layer 1: B16=f16(x@W1[1]), C16=f16(dinv*(x@W1[2])), D16=f16(x@(W1[0]-W1[2])+b1);
    // B16 = dinv*(B16 - 2*dinv*S'(C16)); H = drop(relu(D16 - dinv*S'(B16)))
    k_dense3<<<gDM, 512, 0, stream>>>(x, wt1, b1, dinv, N, B16, C16, D16);
    k_gath1<<<gW32, BLK, 0, stream>>>(C16, B16, dinv, row_ptr, sdst, N);
    k_gath2<<<gW32, BLK, 0, stream>>>(D16, B16, C16h, dmask, dinv, row_ptr, sdst, N);

    // Layer 2: D0->P0 f32, D1->P1h f16 (pitch 32); D2 pre-scaled f16 in B16 (pitch 32);
    // R16 = dinv*(P1 - 2*dinv*S'(D2)); out = lsm(P0 + b2 - dinv*S'(R16))
    k_dense3b<<<gDM, 512, 0, stream>>>(wt2, dinv, N, B16, C16h, P0, P1h);
    k_gath3<<<gW64, BLK, 0, stream>>>(B16, P1h, R16, dinv, row_ptr, sdst, N);
    k_gath4<<<gW64, BLK, 0, stream>>>(R16, P0, dinv, row_ptr, sdst, b2, N, out);
}